// Round 9
// baseline (150.595 us; speedup 1.0000x reference)
//
#include <hip/hip_runtime.h>
#include <hip/hip_cooperative_groups.h>

namespace cg = cooperative_groups;

#define D_ 1024
#define H_ 16
#define HKV_ 4
#define B_ 2
#define S_ 1024
#define BS_ (B_*S_)
#define QKVW 1536
#define QB 64
#define NC (S_/QB)

typedef short bf8 __attribute__((ext_vector_type(8)));
typedef float f32x4 __attribute__((ext_vector_type(4)));

#define MFMA_B16(a,b,c) __builtin_amdgcn_mfma_f32_16x16x32_bf16((a),(b),(c),0,0,0)

// async global->LDS, 16B per lane; LDS dest must be linear in lane order
#define GLOAD16(g, l) __builtin_amdgcn_global_load_lds( \
    (const __attribute__((address_space(1))) void*)(g), \
    (__attribute__((address_space(3))) void*)(l), 16, 0, 0)

// LDS XOR swizzle for [64][64] bf16 tiles: flips 16B-unit within 8-row stripe.
#define SW(row, idx) ((idx) ^ (((row) & 7) << 3))

__device__ __forceinline__ unsigned short f2b(float f) {
  unsigned int u = __float_as_uint(f);
  u += 0x7FFFu + ((u >> 16) & 1u);
  return (unsigned short)(u >> 16);
}
__device__ __forceinline__ float b2f(unsigned short h) {
  return __uint_as_float(((unsigned int)h) << 16);
}
__device__ __forceinline__ float feat(float x) { return x > 0.f ? x + 1.f : __expf(x); }

// ---------- helpers used by the fused prep kernel ----------
__device__ __forceinline__ void conv_body(const float* __restrict__ src,
                                          unsigned short* __restrict__ dst,
                                          int sub, int n4, int tid) {
  int i = sub * 256 + tid;
  if (i >= n4) return;
  float4 v = ((const float4*)src)[i];
  ushort4 o;
  o.x = f2b(v.x); o.y = f2b(v.y); o.z = f2b(v.z); o.w = f2b(v.w);
  ((ushort4*)dst)[i] = o;
}

__device__ __forceinline__ void tconv_body(const float* __restrict__ src,
                                           unsigned short* __restrict__ dst,
                                           int bx, int by, int ss, int ds,
                                           int tid, float (*tl)[65]) {
  int r0 = by * 64, c0 = bx * 64;
  int ty = tid >> 4, tx4 = (tid & 15) * 4;
#pragma unroll
  for (int rep = 0; rep < 4; ++rep) {
    int r = ty + rep * 16;
    float4 v = *(const float4*)&src[(size_t)(r0 + r) * ss + c0 + tx4];
    tl[r][tx4] = v.x; tl[r][tx4 + 1] = v.y; tl[r][tx4 + 2] = v.z; tl[r][tx4 + 3] = v.w;
  }
  __syncthreads();
#pragma unroll
  for (int rep = 0; rep < 4; ++rep) {
    int c = ty + rep * 16;
    ushort4 o;
    o.x = f2b(tl[tx4 + 0][c]); o.y = f2b(tl[tx4 + 1][c]);
    o.z = f2b(tl[tx4 + 2][c]); o.w = f2b(tl[tx4 + 3][c]);
    *(ushort4*)&dst[(size_t)(c0 + c) * ds + r0 + tx4] = o;
  }
}

// ---------- P1: all independent prep + self-contained Wce GEMM ----------
__global__ __launch_bounds__(256) void k_prep(const float* __restrict__ x,
                                              const float* __restrict__ Wq,
                                              const float* __restrict__ Wo,
                                              const float* __restrict__ Wk,
                                              const float* __restrict__ Wv,
                                              const float* __restrict__ Wc,
                                              const float* __restrict__ We,
                                              unsigned short* __restrict__ xb,
                                              unsigned short* __restrict__ Wqkv_t,
                                              unsigned short* __restrict__ Wo_t,
                                              unsigned short* __restrict__ Wkv_b,
                                              float* __restrict__ Wce,
                                              unsigned short* __restrict__ Wce_t) {
  __shared__ float tl[64][65];
  __shared__ __align__(16) unsigned short As[64][72];
  __shared__ __align__(16) unsigned short Bs[128][72];
  int blk = blockIdx.x, tid = threadIdx.x;
  if (blk < 2048) {
    conv_body(x, xb, blk, BS_ * D_ / 4, tid);
  } else if (blk < 2304) {
    conv_body(Wk, Wkv_b, blk - 2048, 1024 * 256 / 4, tid);
  } else if (blk < 2560) {
    conv_body(Wv, Wkv_b + 1024 * 256, blk - 2304, 1024 * 256 / 4, tid);
  } else if (blk < 2816) {
    int sb = blk - 2560;
    tconv_body(Wq, Wqkv_t, sb & 15, sb >> 4, 1024, 1024, tid, tl);
  } else if (blk < 3072) {
    int sb = blk - 2816;
    tconv_body(Wo, Wo_t, sb & 15, sb >> 4, 1024, 1024, tid, tl);
  } else {
    // ---- Wce[256,256] = Wc[256,64] @ We[64,256]; also Wce_t = Wce^T bf16 ----
    int sb = blk - 3072;
    int row0 = (sb >> 1) * 64, col0 = (sb & 1) * 128;
    {
      int r = tid >> 2, c0 = (tid & 3) * 16;
      const float* src = &Wc[(size_t)(row0 + r) * 64 + c0];
#pragma unroll
      for (int e = 0; e < 16; e += 4) {
        float4 v = *(const float4*)(src + e);
        As[r][c0 + e] = f2b(v.x); As[r][c0 + e + 1] = f2b(v.y);
        As[r][c0 + e + 2] = f2b(v.z); As[r][c0 + e + 3] = f2b(v.w);
      }
      int k = tid >> 2, cb = (tid & 3) * 32;
      const float* wsrc = &We[(size_t)k * 256 + col0 + cb];
#pragma unroll
      for (int e = 0; e < 32; e += 4) {
        float4 v = *(const float4*)(wsrc + e);
        Bs[cb + e][k] = f2b(v.x); Bs[cb + e + 1][k] = f2b(v.y);
        Bs[cb + e + 2][k] = f2b(v.z); Bs[cb + e + 3][k] = f2b(v.w);
      }
    }
    __syncthreads();
    const int lane = tid & 63, wave = tid >> 6;
    const int lr = lane & 15, lq = lane >> 4;
    const int wc0 = wave * 32;
    const f32x4 fzero = {0.f, 0.f, 0.f, 0.f};
    f32x4 acc[4][2];
#pragma unroll
    for (int i = 0; i < 4; ++i) { acc[i][0] = fzero; acc[i][1] = fzero; }
#pragma unroll
    for (int kk = 0; kk < 2; ++kk)
#pragma unroll
      for (int mi = 0; mi < 4; ++mi) {
        bf8 a = *(const bf8*)&As[mi * 16 + lr][kk * 32 + lq * 8];
#pragma unroll
        for (int ni = 0; ni < 2; ++ni) {
          bf8 bb = *(const bf8*)&Bs[wc0 + ni * 16 + lr][kk * 32 + lq * 8];
          acc[mi][ni] = MFMA_B16(a, bb, acc[mi][ni]);
        }
      }
#pragma unroll
    for (int mi = 0; mi < 4; ++mi)
#pragma unroll
      for (int ni = 0; ni < 2; ++ni) {
        int col = col0 + wc0 + ni * 16 + lr;
#pragma unroll
        for (int r = 0; r < 4; ++r) {
          int row = row0 + mi * 16 + lq * 4 + r;
          float v = acc[mi][ni][r];
          Wce[(size_t)row * 256 + col] = v;
          Wce_t[(size_t)col * 256 + row] = f2b(v);
        }
      }
  }
}

// ---------- 1-wave 64x64 bt-GEMM: no barriers, dbuf LDS, BK=64, counted vmcnt ----
template<int MODE>
__global__ __launch_bounds__(64) void k_gemm1(const unsigned short* __restrict__ A,
                                              const unsigned short* __restrict__ Bt,
                                              const float* __restrict__ bias,
                                              unsigned short* __restrict__ C,
                                              int N, int K) {
  __shared__ __align__(16) unsigned short As[2][64 * 64];
  __shared__ __align__(16) unsigned short Bs[2][64 * 64];
  const int lane = threadIdx.x;
  const int row0 = blockIdx.y * 64, col0 = blockIdx.x * 64;
  const int lr = lane & 15, lq = lane >> 4;
  const int rsub = lane >> 3, sj = lane & 7;
  const int js = sj ^ rsub;            // swizzled chunk, loop-invariant
  const f32x4 fzero = {0.f, 0.f, 0.f, 0.f};
  f32x4 acc[4][4];
#pragma unroll
  for (int i = 0; i < 4; ++i)
#pragma unroll
    for (int j = 0; j < 4; ++j) acc[i][j] = fzero;

#define STAGE64(pb, k0)                                                        \
  {                                                                            \
    _Pragma("unroll")                                                          \
    for (int i = 0; i < 8; ++i)                                                \
      GLOAD16(&A[(size_t)(row0 + i * 8 + rsub) * K + (k0) + js * 8],           \
              &As[pb][(i * 512 + lane * 8)]);                                  \
    _Pragma("unroll")                                                          \
    for (int i = 0; i < 8; ++i)                                                \
      GLOAD16(&Bt[(size_t)(col0 + i * 8 + rsub) * K + (k0) + js * 8],          \
              &Bs[pb][(i * 512 + lane * 8)]);                                  \
  }

  STAGE64(0, 0);
  int cur = 0;
  for (int k0 = 0; k0 < K; k0 += 64) {
    if (k0 + 64 < K) {
      STAGE64(cur ^ 1, k0 + 64);
      asm volatile("s_waitcnt vmcnt(16)" ::: "memory");
    } else {
      asm volatile("s_waitcnt vmcnt(0)" ::: "memory");
    }
    __builtin_amdgcn_sched_barrier(0);
    bf8 af[2][4], bfr[2][4];
#pragma unroll
    for (int kk = 0; kk < 2; ++kk)
#pragma unroll
      for (int mi = 0; mi < 4; ++mi) {
        int ch = (kk * 4 + lq) ^ (lr & 7);
        af[kk][mi]  = *(const bf8*)&As[cur][(mi * 16 + lr) * 64 + ch * 8];
        bfr[kk][mi] = *(const bf8*)&Bs[cur][(mi * 16 + lr) * 64 + ch * 8];
      }
#pragma unroll
    for (int kk = 0; kk < 2; ++kk)
#pragma unroll
      for (int mi = 0; mi < 4; ++mi)
#pragma unroll
        for (int ni = 0; ni < 4; ++ni)
          acc[mi][ni] = MFMA_B16(af[kk][mi], bfr[kk][ni], acc[mi][ni]);
    cur ^= 1;
  }
#undef STAGE64
#pragma unroll
  for (int ni = 0; ni < 4; ++ni) {
    int col = col0 + ni * 16 + lr;
    float bv = bias[col];
#pragma unroll
    for (int mi = 0; mi < 4; ++mi)
#pragma unroll
      for (int r = 0; r < 4; ++r) {
        int row = row0 + mi * 16 + lq * 4 + r;
        float v = acc[mi][ni][r] + bv;
        if (MODE == 1 && col < 1280) v = feat(v);
        C[(size_t)row * N + col] = f2b(v);
      }
  }
}

// ---------- weight-fold bt-GEMM (P3), 64x128 tile, 2 waves ----------
__global__ __launch_bounds__(128) void k_fold(const unsigned short* __restrict__ A,
                                              const unsigned short* __restrict__ Bt,
                                              unsigned short* __restrict__ C,
                                              float* __restrict__ biasq,
                                              int N, int K,
                                              const float* __restrict__ fbq,
                                              const float* __restrict__ fbk,
                                              const float* __restrict__ fbv,
                                              const float* __restrict__ fWce) {
  if (blockIdx.y == 4) {
    int t = blockIdx.x * 128 + threadIdx.x;
    if (t >= QKVW) return;
    if (t < 1024) { biasq[t] = fbq[t]; return; }
    const float* b = (t < 1280) ? fbk : fbv;
    int n = (t < 1280) ? (t - 1024) : (t - 1280);
    float s = 0.f;
    for (int j = 0; j < 256; ++j) s += b[j] * fWce[j * 256 + n];
    biasq[t] = s;
    return;
  }
  __shared__ __align__(16) unsigned short As[64 * 32];
  __shared__ __align__(16) unsigned short Bs[128 * 32];
  const int tid = threadIdx.x;
  const int lane = tid & 63, wave = tid >> 6;
  const int row0 = blockIdx.y * 64, col0 = blockIdx.x * 128;
  const f32x4 fzero = {0.f, 0.f, 0.f, 0.f};
  f32x4 acc[4][4];
#pragma unroll
  for (int i = 0; i < 4; ++i)
#pragma unroll
    for (int j = 0; j < 4; ++j) acc[i][j] = fzero;
  const int lr = lane & 15, lq = lane >> 4, lk = lq * 8;
  for (int k0 = 0; k0 < K; k0 += 32) {
#pragma unroll
    for (int i = 0; i < 2; ++i) {
      int e = (tid + i * 128) * 8;
      int r = e >> 5, c = e & 31;
      GLOAD16(&A[(size_t)(row0 + r) * K + k0 + c], &As[e]);
    }
#pragma unroll
    for (int i = 0; i < 4; ++i) {
      int e = (tid + i * 128) * 8;
      int r = e >> 5, c = e & 31;
      GLOAD16(&Bt[(size_t)(col0 + r) * K + k0 + c], &Bs[e]);
    }
    __syncthreads();
    bf8 af[4], bfr[4];
#pragma unroll
    for (int mi = 0; mi < 4; ++mi)
      af[mi] = *(const bf8*)&As[(mi * 16 + lr) * 32 + lk];
#pragma unroll
    for (int ni = 0; ni < 4; ++ni)
      bfr[ni] = *(const bf8*)&Bs[(wave * 64 + ni * 16 + lr) * 32 + lk];
#pragma unroll
    for (int mi = 0; mi < 4; ++mi)
#pragma unroll
      for (int ni = 0; ni < 4; ++ni)
        acc[mi][ni] = MFMA_B16(af[mi], bfr[ni], acc[mi][ni]);
    __syncthreads();
  }
#pragma unroll
  for (int mi = 0; mi < 4; ++mi)
#pragma unroll
    for (int ni = 0; ni < 4; ++ni) {
      int col = col0 + wave * 64 + ni * 16 + lr;
#pragma unroll
      for (int r = 0; r < 4; ++r) {
        int row = row0 + mi * 16 + lq * 4 + r;
        int sec = col >> 10, cc = col & 1023;
        C[(size_t)(1024 + sec * 256 + row) * 1024 + cc] = f2b(acc[mi][ni][r]);
      }
    }
}

// ---------- cooperative fused: chunk-sums -> scan -> attention ----------
// grid = 256 blocks (c,hp,b) x 512 threads, 1 block/CU. K/V/Q persist in LDS
// across grid syncs; V transposed in-LDS (vt buffer eliminated).
__global__ __launch_bounds__(512) void k_fused(const unsigned short* __restrict__ qkvb,
                                               float* __restrict__ stc,
                                               unsigned short* __restrict__ stp,
                                               float* __restrict__ zp,
                                               unsigned short* __restrict__ ob) {
  cg::grid_group gg = cg::this_grid();
  __shared__ __align__(16) unsigned short Qf[2][64 * 64];
  __shared__ __align__(16) unsigned short Kf[64 * 64];
  __shared__ __align__(16) unsigned short Vl[64 * 64];
  __shared__ __align__(16) unsigned short Sl[64 * 64];
  __shared__ __align__(16) unsigned short P[2][64 * 64];
  __shared__ __align__(16) unsigned short Ol[64][144];   // V staging, then O staging
  __shared__ float zl[64];
  __shared__ float den[2][64];
  int bid = blockIdx.x;
  int c = bid & 15, hp = (bid >> 4) & 7, b = bid >> 7;
  int g = hp >> 1;
  int tid = threadIdx.x, lane = tid & 63, wave = tid >> 6;
  int s0 = c * QB;
  // ---- phase A: load Q(2 heads), K(featted), raw V -> Ol staging ----
  {
    int hsel = tid >> 8, t = tid & 255;
    int j = t >> 2, f0 = (t & 3) * 16;
    const unsigned short* qr =
        &qkvb[(size_t)(b * S_ + s0 + j) * QKVW + (hp * 2 + hsel) * 64 + f0];
    *(uint4*)&Qf[hsel][SW(j, j * 64 + f0)]     = *(const uint4*)qr;
    *(uint4*)&Qf[hsel][SW(j, j * 64 + f0 + 8)] = *(const uint4*)(qr + 8);
    if (tid < 256) {
      const unsigned short* kr =
          &qkvb[(size_t)(b * S_ + s0 + j) * QKVW + 1024 + g * 64 + f0];
      *(uint4*)&Kf[SW(j, j * 64 + f0)]     = *(const uint4*)kr;
      *(uint4*)&Kf[SW(j, j * 64 + f0 + 8)] = *(const uint4*)(kr + 8);
    } else {
      const unsigned short* vr =
          &qkvb[(size_t)(b * S_ + s0 + j) * QKVW + 1280 + g * 64 + f0];
      *(uint4*)&Ol[j][f0]     = *(const uint4*)vr;
      *(uint4*)&Ol[j][f0 + 8] = *(const uint4*)(vr + 8);
    }
  }
  __syncthreads();
  // V transpose: Ol[s][d] -> Vl[d][s] (swizzled)
  {
    int d = tid >> 3, sq = (tid & 7) * 8;
    unsigned short tmp[8];
#pragma unroll
    for (int e = 0; e < 8; ++e) tmp[e] = Ol[sq + e][d];
    *(uint4*)&Vl[SW(d, d * 64 + sq)] = *(const uint4*)tmp;
  }
  __syncthreads();
  // chunk sums: one block per (b,g,c) — even hp only
  if ((hp & 1) == 0) {
    int d = tid >> 3, f0 = (tid & 7) * 8;
    float acc[8];
#pragma unroll
    for (int e = 0; e < 8; ++e) acc[e] = 0.f;
    for (int s = 0; s < 64; ++s) {
      float vv = b2f(Vl[SW(d, d * 64 + s)]);
      int kb = SW(s, s * 64 + f0);
#pragma unroll
      for (int e = 0; e < 8; ++e) acc[e] += vv * b2f(Kf[kb + e]);
    }
    size_t base = ((size_t)((b * HKV_ + g) * NC + c) * 65 + d) * 64 + f0;
#pragma unroll
    for (int e = 0; e < 8; ++e) stc[base + e] = acc[e];
    if (tid < 64) {
      float z = 0.f;
      for (int s = 0; s < 64; ++s) z += b2f(Kf[SW(s, s * 64 + tid)]);
      stc[((size_t)((b * HKV_ + g) * NC + c) * 65 + 64) * 64 + tid] = z;
    }
  }
  gg.sync();
  // ---- phase B: exclusive chunk-prefix (blocks 0..64 cover 8*65*64 elems) ----
  if (bid < 65) {
    int t = bid * 512 + tid;
    int bg = t / (65 * 64);
    int e = t - bg * (65 * 64);
    int d = e >> 6, f = e & 63;
    float run = 0.f;
#pragma unroll
    for (int cc = 0; cc < NC; ++cc) {
      if (d < 64) stp[(size_t)(bg * NC + cc) * 4096 + e] = f2b(run);
      else        zp[(bg * NC + cc) * 64 + f] = run;
      run += stc[((size_t)(bg * NC + cc) * 65 + d) * 64 + f];
    }
  }
  gg.sync();
  // ---- phase C: attention (Q/K/V still in LDS) ----
  {
    const unsigned short* sbase = &stp[(size_t)((b * HKV_ + g) * NC + c) * 4096];
    int dd = tid >> 3;
    *(uint4*)&Sl[SW(dd, tid * 8)] = *(const uint4*)&sbase[tid * 8];
    if (tid < 64) zl[tid] = zp[((b * HKV_ + g) * NC + c) * 64 + tid];
  }
  __syncthreads();
  const int lr = lane & 15, lq = lane >> 4, lk = lq * 8;
  const int hh = wave >> 2, rw = (wave & 3) * 16;
  const f32x4 fzero = {0.f, 0.f, 0.f, 0.f};
  bf8 aQ[2];
#pragma unroll
  for (int kk = 0; kk < 2; ++kk)
    aQ[kk] = *(const bf8*)&Qf[hh][SW(rw + lr, (rw + lr) * 64 + kk * 32 + lk)];
  f32x4 sc[4];
#pragma unroll
  for (int nj = 0; nj < 4; ++nj) sc[nj] = fzero;
#pragma unroll
  for (int nj = 0; nj < 4; ++nj)
#pragma unroll
    for (int kk = 0; kk < 2; ++kk) {
      bf8 bk8 = *(const bf8*)&Kf[SW(nj * 16 + lr, (nj * 16 + lr) * 64 + kk * 32 + lk)];
      sc[nj] = MFMA_B16(aQ[kk], bk8, sc[nj]);
    }
#pragma unroll
  for (int nj = 0; nj < 4; ++nj)
#pragma unroll
    for (int r = 0; r < 4; ++r) {
      int i = rw + lq * 4 + r;
      int j = nj * 16 + lr;
      float v = (j <= i) ? sc[nj][r] : 0.f;
      P[hh][SW(i, i * 64 + j)] = f2b(v);
    }
  __syncthreads();
  {
    int hd = tid >> 8, t = tid & 255;
    int i = t >> 2, q = t & 3, f0 = q * 16;
    float s = 0.f;
#pragma unroll
    for (int e = 0; e < 16; ++e) s += b2f(P[hd][SW(i, i * 64 + f0 + e)]);
#pragma unroll
    for (int e = 0; e < 16; ++e) s += b2f(Qf[hd][SW(i, i * 64 + f0 + e)]) * zl[f0 + e];
    s += __shfl_xor(s, 1);
    s += __shfl_xor(s, 2);
    if (q == 0) den[hd][i] = s;
  }
  f32x4 oa[4];
#pragma unroll
  for (int nd = 0; nd < 4; ++nd) oa[nd] = fzero;
  bf8 aP[2];
#pragma unroll
  for (int kk = 0; kk < 2; ++kk)
    aP[kk] = *(const bf8*)&P[hh][SW(rw + lr, (rw + lr) * 64 + kk * 32 + lk)];
#pragma unroll
  for (int nd = 0; nd < 4; ++nd)
#pragma unroll
    for (int kk = 0; kk < 2; ++kk) {
      bf8 bS = *(const bf8*)&Sl[SW(nd * 16 + lr, (nd * 16 + lr) * 64 + kk * 32 + lk)];
      oa[nd] = MFMA_B16(aQ[kk], bS, oa[nd]);
      bf8 bV = *(const bf8*)&Vl[SW(nd * 16 + lr, (nd * 16 + lr) * 64 + kk * 32 + lk)];
      oa[nd] = MFMA_B16(aP[kk], bV, oa[nd]);
    }
  __syncthreads();
#pragma unroll
  for (int nd = 0; nd < 4; ++nd)
#pragma unroll
    for (int r = 0; r < 4; ++r) {
      int i = rw + lq * 4 + r;
      int dd = nd * 16 + lr;
      Ol[i][hh * 64 + dd] = f2b(oa[nd][r] / (den[hh][i] + 1e-6f));
    }
  __syncthreads();
  {
    int j = tid >> 3, u = tid & 7;
    unsigned short* orow = &ob[(size_t)(b * S_ + s0 + j) * D_ + hp * 128 + u * 16];
    *(uint4*)orow       = *(const uint4*)&Ol[j][u * 16];
    *(uint4*)(orow + 8) = *(const uint4*)&Ol[j][u * 16 + 8];
  }
}

// ------- residual + LayerNorm (bf16 x, bf16 o2) -------
__global__ __launch_bounds__(256) void k_ln(const unsigned short* __restrict__ xb,
                                            const unsigned short* __restrict__ o2,
                                            const float* __restrict__ gamma,
                                            const float* __restrict__ beta,
                                            float* __restrict__ out) {
  int row = blockIdx.x, tid = threadIdx.x;
  ushort4 xv = ((const ushort4*)(xb + (size_t)row * D_))[tid];
  ushort4 ov = ((const ushort4*)(o2 + (size_t)row * D_))[tid];
  float4 y;
  y.x = b2f(xv.x) + b2f(ov.x); y.y = b2f(xv.y) + b2f(ov.y);
  y.z = b2f(xv.z) + b2f(ov.z); y.w = b2f(xv.w) + b2f(ov.w);
  float s = y.x + y.y + y.z + y.w;
  float ss = y.x * y.x + y.y * y.y + y.z * y.z + y.w * y.w;
#pragma unroll
  for (int off = 32; off > 0; off >>= 1) {
    s += __shfl_down(s, off);
    ss += __shfl_down(ss, off);
  }
  __shared__ float red[8];
  int lane = tid & 63, wave = tid >> 6;
  if (lane == 0) { red[wave] = s; red[4 + wave] = ss; }
  __syncthreads();
  if (tid == 0) {
    red[0] = red[0] + red[1] + red[2] + red[3];
    red[4] = red[4] + red[5] + red[6] + red[7];
  }
  __syncthreads();
  float mu = red[0] * (1.f / D_);
  float var = red[4] * (1.f / D_) - mu * mu;
  float rs = rsqrtf(var + 1e-5f);
  float4 g4 = ((const float4*)gamma)[tid];
  float4 b4 = ((const float4*)beta)[tid];
  float4 o;
  o.x = (y.x - mu) * rs * g4.x + b4.x;
  o.y = (y.y - mu) * rs * g4.y + b4.y;
  o.z = (y.z - mu) * rs * g4.z + b4.z;
  o.w = (y.w - mu) * rs * g4.w + b4.w;
  ((float4*)(out + (size_t)row * D_))[tid] = o;
}

extern "C" void kernel_launch(void* const* d_in, const int* in_sizes, int n_in,
                              void* d_out, int out_size, void* d_ws, size_t ws_size,
                              hipStream_t stream) {
  const float* x     = (const float*)d_in[0];
  const float* Wq    = (const float*)d_in[1];
  const float* bq    = (const float*)d_in[2];
  const float* Wk    = (const float*)d_in[3];
  const float* bk    = (const float*)d_in[4];
  const float* Wv    = (const float*)d_in[5];
  const float* bv    = (const float*)d_in[6];
  const float* Wc    = (const float*)d_in[7];
  const float* We    = (const float*)d_in[8];
  const float* Wo    = (const float*)d_in[9];
  const float* bo    = (const float*)d_in[10];
  const float* gamma = (const float*)d_in[11];
  const float* beta  = (const float*)d_in[12];

  char* p = (char*)d_ws;
  size_t off = 0;
  auto carve = [&](size_t bytes) {
    void* r = p + off;
    off = (off + bytes + 255) & ~(size_t)255;
    return r;
  };
  unsigned short* xb     = (unsigned short*)carve((size_t)BS_ * D_ * 2);
  unsigned short* Wqkv_t = (unsigned short*)carve((size_t)QKVW * D_ * 2);
  unsigned short* Wo_t   = (unsigned short*)carve((size_t)D_ * D_ * 2);
  float*          biasq  = (float*)carve(QKVW * 4);
  unsigned short* qkvb   = (unsigned short*)carve((size_t)BS_ * QKVW * 2);
  float*          Wce    = (float*)carve(256 * 256 * 4);
  unsigned short* Wce_t  = (unsigned short*)carve(256 * 256 * 2);
  unsigned short* Wkv_b  = (unsigned short*)carve((size_t)2048 * 256 * 2);
  float*          stc    = (float*)carve((size_t)8 * NC * 65 * 64 * 4);
  unsigned short* stp    = (unsigned short*)carve((size_t)8 * NC * 4096 * 2);
  float*          zp     = (float*)carve((size_t)8 * NC * 64 * 4);
  unsigned short* obuf   = (unsigned short*)carve((size_t)BS_ * D_ * 2);
  unsigned short* o2     = (unsigned short*)carve((size_t)BS_ * D_ * 2);

  // P1: prep + self-contained Wce GEMM
  k_prep<<<3080, 256, 0, stream>>>(x, Wq, Wo, Wk, Wv, Wc, We,
                                   xb, Wqkv_t, Wo_t, Wkv_b, Wce, Wce_t);
  // P3: folded K/V weights into Wqkv_t rows [1024,1536) + bias fold
  k_fold<<<dim3(16, 5), 128, 0, stream>>>(Wce_t, Wkv_b, Wqkv_t, biasq,
                                          2048, 256, bq, bk, bv, Wce);
  // P4: fused QKV projection -> qkvb bf16 (Q,K pre-featted)
  k_gemm1<1><<<dim3(24, 32), 64, 0, stream>>>(xb, Wqkv_t, biasq, qkvb, QKVW, 1024);
  // P5: cooperative fused chunk-sums + scan + attention
  {
    void* args[] = {(void*)&qkvb, (void*)&stc, (void*)&stp, (void*)&zp, (void*)&obuf};
    hipLaunchCooperativeKernel((const void*)k_fused, dim3(256), dim3(512),
                               args, 0, stream);
  }
  // P7: output projection -> o2 bf16
  k_gemm1<0><<<dim3(16, 32), 64, 0, stream>>>(obuf, Wo_t, bo, o2, 1024, 1024);
  // P8: residual + LayerNorm (bf16 inputs)
  k_ln<<<BS_, 256, 0, stream>>>(xb, o2, gamma, beta, (float*)d_out);
}

// Round 10
// 87.576 us; speedup vs baseline: 1.7196x; 1.7196x over previous
//
#include <hip/hip_runtime.h>

#define D_ 1024
#define H_ 16
#define HKV_ 4
#define B_ 2
#define S_ 1024
#define BS_ (B_*S_)
#define QKVW 1536
#define QB 64
#define NC (S_/QB)

typedef short bf8 __attribute__((ext_vector_type(8)));
typedef float f32x4 __attribute__((ext_vector_type(4)));

#define MFMA_B16(a,b,c) __builtin_amdgcn_mfma_f32_16x16x32_bf16((a),(b),(c),0,0,0)

// async global->LDS, 16B per lane; LDS dest must be linear in lane order
#define GLOAD16(g, l) __builtin_amdgcn_global_load_lds( \
    (const __attribute__((address_space(1))) void*)(g), \
    (__attribute__((address_space(3))) void*)(l), 16, 0, 0)

// LDS XOR swizzle for [64][64] bf16 tiles: flips 16B-unit within 8-row stripe.
#define SW(row, idx) ((idx) ^ (((row) & 7) << 3))

__device__ __forceinline__ unsigned short f2b(float f) {
  unsigned int u = __float_as_uint(f);
  u += 0x7FFFu + ((u >> 16) & 1u);
  return (unsigned short)(u >> 16);
}
__device__ __forceinline__ float b2f(unsigned short h) {
  return __uint_as_float(((unsigned int)h) << 16);
}
__device__ __forceinline__ float feat(float x) { return x > 0.f ? x + 1.f : __expf(x); }

// ---------- helpers used by the fused prep kernel ----------
__device__ __forceinline__ void conv_body(const float* __restrict__ src,
                                          unsigned short* __restrict__ dst,
                                          int sub, int n4, int tid) {
  int i = sub * 256 + tid;
  if (i >= n4) return;
  float4 v = ((const float4*)src)[i];
  ushort4 o;
  o.x = f2b(v.x); o.y = f2b(v.y); o.z = f2b(v.z); o.w = f2b(v.w);
  ((ushort4*)dst)[i] = o;
}

__device__ __forceinline__ void tconv_body(const float* __restrict__ src,
                                           unsigned short* __restrict__ dst,
                                           int bx, int by, int ss, int ds,
                                           int tid, float (*tl)[65]) {
  int r0 = by * 64, c0 = bx * 64;
  int ty = tid >> 4, tx4 = (tid & 15) * 4;
#pragma unroll
  for (int rep = 0; rep < 4; ++rep) {
    int r = ty + rep * 16;
    float4 v = *(const float4*)&src[(size_t)(r0 + r) * ss + c0 + tx4];
    tl[r][tx4] = v.x; tl[r][tx4 + 1] = v.y; tl[r][tx4 + 2] = v.z; tl[r][tx4 + 3] = v.w;
  }
  __syncthreads();
#pragma unroll
  for (int rep = 0; rep < 4; ++rep) {
    int c = ty + rep * 16;
    ushort4 o;
    o.x = f2b(tl[tx4 + 0][c]); o.y = f2b(tl[tx4 + 1][c]);
    o.z = f2b(tl[tx4 + 2][c]); o.w = f2b(tl[tx4 + 3][c]);
    *(ushort4*)&dst[(size_t)(c0 + c) * ds + r0 + tx4] = o;
  }
}

// ---------- P1: all independent prep + self-contained Wce GEMM ----------
__global__ __launch_bounds__(256) void k_prep(const float* __restrict__ x,
                                              const float* __restrict__ Wq,
                                              const float* __restrict__ Wo,
                                              const float* __restrict__ Wk,
                                              const float* __restrict__ Wv,
                                              const float* __restrict__ Wc,
                                              const float* __restrict__ We,
                                              unsigned short* __restrict__ xb,
                                              unsigned short* __restrict__ Wqkv_t,
                                              unsigned short* __restrict__ Wo_t,
                                              unsigned short* __restrict__ Wkv_b,
                                              float* __restrict__ Wce,
                                              unsigned short* __restrict__ Wce_t) {
  __shared__ float tl[64][65];
  __shared__ __align__(16) unsigned short As[64][72];
  __shared__ __align__(16) unsigned short Bs[128][72];
  int blk = blockIdx.x, tid = threadIdx.x;
  if (blk < 2048) {
    conv_body(x, xb, blk, BS_ * D_ / 4, tid);
  } else if (blk < 2304) {
    conv_body(Wk, Wkv_b, blk - 2048, 1024 * 256 / 4, tid);
  } else if (blk < 2560) {
    conv_body(Wv, Wkv_b + 1024 * 256, blk - 2304, 1024 * 256 / 4, tid);
  } else if (blk < 2816) {
    int sb = blk - 2560;
    tconv_body(Wq, Wqkv_t, sb & 15, sb >> 4, 1024, 1024, tid, tl);
  } else if (blk < 3072) {
    int sb = blk - 2816;
    tconv_body(Wo, Wo_t, sb & 15, sb >> 4, 1024, 1024, tid, tl);
  } else {
    // ---- Wce[256,256] = Wc[256,64] @ We[64,256]; also Wce_t = Wce^T bf16 ----
    int sb = blk - 3072;
    int row0 = (sb >> 1) * 64, col0 = (sb & 1) * 128;
    {
      int r = tid >> 2, c0 = (tid & 3) * 16;
      const float* src = &Wc[(size_t)(row0 + r) * 64 + c0];
#pragma unroll
      for (int e = 0; e < 16; e += 4) {
        float4 v = *(const float4*)(src + e);
        As[r][c0 + e] = f2b(v.x); As[r][c0 + e + 1] = f2b(v.y);
        As[r][c0 + e + 2] = f2b(v.z); As[r][c0 + e + 3] = f2b(v.w);
      }
      int k = tid >> 2, cb = (tid & 3) * 32;
      const float* wsrc = &We[(size_t)k * 256 + col0 + cb];
#pragma unroll
      for (int e = 0; e < 32; e += 4) {
        float4 v = *(const float4*)(wsrc + e);
        Bs[cb + e][k] = f2b(v.x); Bs[cb + e + 1][k] = f2b(v.y);
        Bs[cb + e + 2][k] = f2b(v.z); Bs[cb + e + 3][k] = f2b(v.w);
      }
    }
    __syncthreads();
    const int lane = tid & 63, wave = tid >> 6;
    const int lr = lane & 15, lq = lane >> 4;
    const int wc0 = wave * 32;
    const f32x4 fzero = {0.f, 0.f, 0.f, 0.f};
    f32x4 acc[4][2];
#pragma unroll
    for (int i = 0; i < 4; ++i) { acc[i][0] = fzero; acc[i][1] = fzero; }
#pragma unroll
    for (int kk = 0; kk < 2; ++kk)
#pragma unroll
      for (int mi = 0; mi < 4; ++mi) {
        bf8 a = *(const bf8*)&As[mi * 16 + lr][kk * 32 + lq * 8];
#pragma unroll
        for (int ni = 0; ni < 2; ++ni) {
          bf8 bb = *(const bf8*)&Bs[wc0 + ni * 16 + lr][kk * 32 + lq * 8];
          acc[mi][ni] = MFMA_B16(a, bb, acc[mi][ni]);
        }
      }
#pragma unroll
    for (int mi = 0; mi < 4; ++mi)
#pragma unroll
      for (int ni = 0; ni < 2; ++ni) {
        int col = col0 + wc0 + ni * 16 + lr;
#pragma unroll
        for (int r = 0; r < 4; ++r) {
          int row = row0 + mi * 16 + lq * 4 + r;
          float v = acc[mi][ni][r];
          Wce[(size_t)row * 256 + col] = v;
          Wce_t[(size_t)col * 256 + row] = f2b(v);
        }
      }
  }
}

// ---------- 1-wave 64x64 bt-GEMM: no barriers, dbuf LDS, BK=64, counted vmcnt ----
template<int MODE>
__global__ __launch_bounds__(64) void k_gemm1(const unsigned short* __restrict__ A,
                                              const unsigned short* __restrict__ Bt,
                                              const float* __restrict__ bias,
                                              unsigned short* __restrict__ C,
                                              int N, int K) {
  __shared__ __align__(16) unsigned short As[2][64 * 64];
  __shared__ __align__(16) unsigned short Bs[2][64 * 64];
  const int lane = threadIdx.x;
  const int row0 = blockIdx.y * 64, col0 = blockIdx.x * 64;
  const int lr = lane & 15, lq = lane >> 4;
  const int rsub = lane >> 3, sj = lane & 7;
  const int js = sj ^ rsub;            // swizzled chunk, loop-invariant
  const f32x4 fzero = {0.f, 0.f, 0.f, 0.f};
  f32x4 acc[4][4];
#pragma unroll
  for (int i = 0; i < 4; ++i)
#pragma unroll
    for (int j = 0; j < 4; ++j) acc[i][j] = fzero;

#define STAGE64(pb, k0)                                                        \
  {                                                                            \
    _Pragma("unroll")                                                          \
    for (int i = 0; i < 8; ++i)                                                \
      GLOAD16(&A[(size_t)(row0 + i * 8 + rsub) * K + (k0) + js * 8],           \
              &As[pb][(i * 512 + lane * 8)]);                                  \
    _Pragma("unroll")                                                          \
    for (int i = 0; i < 8; ++i)                                                \
      GLOAD16(&Bt[(size_t)(col0 + i * 8 + rsub) * K + (k0) + js * 8],          \
              &Bs[pb][(i * 512 + lane * 8)]);                                  \
  }

  STAGE64(0, 0);
  int cur = 0;
  for (int k0 = 0; k0 < K; k0 += 64) {
    if (k0 + 64 < K) {
      STAGE64(cur ^ 1, k0 + 64);
      asm volatile("s_waitcnt vmcnt(16)" ::: "memory");
    } else {
      asm volatile("s_waitcnt vmcnt(0)" ::: "memory");
    }
    __builtin_amdgcn_sched_barrier(0);
    bf8 af[2][4], bfr[2][4];
#pragma unroll
    for (int kk = 0; kk < 2; ++kk)
#pragma unroll
      for (int mi = 0; mi < 4; ++mi) {
        int ch = (kk * 4 + lq) ^ (lr & 7);
        af[kk][mi]  = *(const bf8*)&As[cur][(mi * 16 + lr) * 64 + ch * 8];
        bfr[kk][mi] = *(const bf8*)&Bs[cur][(mi * 16 + lr) * 64 + ch * 8];
      }
#pragma unroll
    for (int kk = 0; kk < 2; ++kk)
#pragma unroll
      for (int mi = 0; mi < 4; ++mi)
#pragma unroll
        for (int ni = 0; ni < 4; ++ni)
          acc[mi][ni] = MFMA_B16(af[kk][mi], bfr[kk][ni], acc[mi][ni]);
    cur ^= 1;
  }
#undef STAGE64
#pragma unroll
  for (int ni = 0; ni < 4; ++ni) {
    int col = col0 + ni * 16 + lr;
    float bv = bias[col];
#pragma unroll
    for (int mi = 0; mi < 4; ++mi)
#pragma unroll
      for (int r = 0; r < 4; ++r) {
        int row = row0 + mi * 16 + lq * 4 + r;
        float v = acc[mi][ni][r] + bv;
        if (MODE == 1 && col < 1280) v = feat(v);
        C[(size_t)row * N + col] = f2b(v);
      }
  }
}

// ---------- weight-fold bt-GEMM (P3), 64x128 tile, 2 waves ----------
__global__ __launch_bounds__(128) void k_fold(const unsigned short* __restrict__ A,
                                              const unsigned short* __restrict__ Bt,
                                              unsigned short* __restrict__ C,
                                              float* __restrict__ biasq,
                                              int N, int K,
                                              const float* __restrict__ fbq,
                                              const float* __restrict__ fbk,
                                              const float* __restrict__ fbv,
                                              const float* __restrict__ fWce) {
  if (blockIdx.y == 4) {
    int t = blockIdx.x * 128 + threadIdx.x;
    if (t >= QKVW) return;
    if (t < 1024) { biasq[t] = fbq[t]; return; }
    const float* b = (t < 1280) ? fbk : fbv;
    int n = (t < 1280) ? (t - 1024) : (t - 1280);
    float s = 0.f;
    for (int j = 0; j < 256; ++j) s += b[j] * fWce[j * 256 + n];
    biasq[t] = s;
    return;
  }
  __shared__ __align__(16) unsigned short As[64 * 32];
  __shared__ __align__(16) unsigned short Bs[128 * 32];
  const int tid = threadIdx.x;
  const int lane = tid & 63, wave = tid >> 6;
  const int row0 = blockIdx.y * 64, col0 = blockIdx.x * 128;
  const f32x4 fzero = {0.f, 0.f, 0.f, 0.f};
  f32x4 acc[4][4];
#pragma unroll
  for (int i = 0; i < 4; ++i)
#pragma unroll
    for (int j = 0; j < 4; ++j) acc[i][j] = fzero;
  const int lr = lane & 15, lq = lane >> 4, lk = lq * 8;
  for (int k0 = 0; k0 < K; k0 += 32) {
#pragma unroll
    for (int i = 0; i < 2; ++i) {
      int e = (tid + i * 128) * 8;
      int r = e >> 5, c = e & 31;
      GLOAD16(&A[(size_t)(row0 + r) * K + k0 + c], &As[e]);
    }
#pragma unroll
    for (int i = 0; i < 4; ++i) {
      int e = (tid + i * 128) * 8;
      int r = e >> 5, c = e & 31;
      GLOAD16(&Bt[(size_t)(col0 + r) * K + k0 + c], &Bs[e]);
    }
    __syncthreads();
    bf8 af[4], bfr[4];
#pragma unroll
    for (int mi = 0; mi < 4; ++mi)
      af[mi] = *(const bf8*)&As[(mi * 16 + lr) * 32 + lk];
#pragma unroll
    for (int ni = 0; ni < 4; ++ni)
      bfr[ni] = *(const bf8*)&Bs[(wave * 64 + ni * 16 + lr) * 32 + lk];
#pragma unroll
    for (int mi = 0; mi < 4; ++mi)
#pragma unroll
      for (int ni = 0; ni < 4; ++ni)
        acc[mi][ni] = MFMA_B16(af[mi], bfr[ni], acc[mi][ni]);
    __syncthreads();
  }
#pragma unroll
  for (int mi = 0; mi < 4; ++mi)
#pragma unroll
    for (int ni = 0; ni < 4; ++ni) {
      int col = col0 + wave * 64 + ni * 16 + lr;
#pragma unroll
      for (int r = 0; r < 4; ++r) {
        int row = row0 + mi * 16 + lq * 4 + r;
        int sec = col >> 10, cc = col & 1023;
        C[(size_t)(1024 + sec * 256 + row) * 1024 + cc] = f2b(acc[mi][ni][r]);
      }
    }
}

// ---------- per-chunk KV sums only (V transpose for attn now in-LDS there) ----------
__global__ __launch_bounds__(256) void k_vkv(const unsigned short* __restrict__ qkvb,
                                             float* __restrict__ stc) {
  __shared__ unsigned short tl[64][72];   // V staging (raw bf16), [s][d]
  __shared__ float Kf[64 * 64];
  int c = blockIdx.x, g = blockIdx.y, b = blockIdx.z;
  int tid = threadIdx.x;
  int s0 = c * QB;
  {
    int j = tid >> 2, f0 = (tid & 3) * 16;
    const unsigned short* kr = &qkvb[(size_t)(b * S_ + s0 + j) * QKVW + 1024 + g * 64 + f0];
    const unsigned short* vr = &qkvb[(size_t)(b * S_ + s0 + j) * QKVW + 1280 + g * 64 + f0];
    uint4 k0_ = *(const uint4*)kr;
    uint4 k1_ = *(const uint4*)(kr + 8);
    const unsigned short* ks = (const unsigned short*)&k0_;
#pragma unroll
    for (int e = 0; e < 8; ++e) Kf[j * 64 + f0 + e] = b2f(ks[e]);
    ks = (const unsigned short*)&k1_;
#pragma unroll
    for (int e = 0; e < 8; ++e) Kf[j * 64 + f0 + 8 + e] = b2f(ks[e]);
    *(uint4*)&tl[j][f0] = *(const uint4*)vr;
    *(uint4*)&tl[j][f0 + 8] = *(const uint4*)(vr + 8);
  }
  __syncthreads();
  // per-chunk sums St_c[d][f] and z_c[f]
  int d = tid >> 2, f0 = (tid & 3) * 16;
  float acc[16];
#pragma unroll
  for (int e = 0; e < 16; ++e) acc[e] = 0.f;
#pragma unroll 4
  for (int j = 0; j < QB; ++j) {
    float vv = b2f(tl[j][d]);
    const float* kfr = &Kf[j * 64 + f0];
#pragma unroll
    for (int e = 0; e < 16; ++e) acc[e] += vv * kfr[e];
  }
  size_t base = ((size_t)((b * HKV_ + g) * NC + c) * 65 + d) * 64 + f0;
#pragma unroll
  for (int e = 0; e < 16; ++e) stc[base + e] = acc[e];
  if (tid < 64) {
    float z = 0.f;
    for (int j = 0; j < QB; ++j) z += Kf[j * 64 + tid];
    stc[((size_t)((b * HKV_ + g) * NC + c) * 65 + 64) * 64 + tid] = z;
  }
}

// ---------- per-(chunk, head-pair) attention + inline exclusive prefix ----------
// Prefix over chunk sums computed here (vectorized float4, 4 independent
// partials — R3's serial-scalar mistake avoided). No stp/zp/vt buffers.
__global__ __launch_bounds__(512) void k_attn(const unsigned short* __restrict__ qkvb,
                                              const float* __restrict__ stc,
                                              unsigned short* __restrict__ ob) {
  __shared__ __align__(16) unsigned short Qf[2][64 * 64];
  __shared__ __align__(16) unsigned short Kf[64 * 64];
  __shared__ __align__(16) unsigned short Vl[64 * 64];
  __shared__ __align__(16) unsigned short Sl[64 * 64];
  __shared__ __align__(16) unsigned short P[2][64 * 64];
  __shared__ __align__(16) unsigned short Ol[64][144];  // V staging, then O staging
  __shared__ float zl[64];
  __shared__ float den[2][64];
  int c = blockIdx.x, hp = blockIdx.y, b = blockIdx.z;
  int g = hp >> 1;
  int tid = threadIdx.x, lane = tid & 63, wave = tid >> 6;
  int s0 = c * QB;
  // ---- load Q (2 heads), K, V(rows -> Ol) ----
  {
    int hsel = tid >> 8, t = tid & 255;
    int j = t >> 2, f0 = (t & 3) * 16;
    const unsigned short* qr =
        &qkvb[(size_t)(b * S_ + s0 + j) * QKVW + (hp * 2 + hsel) * 64 + f0];
    *(uint4*)&Qf[hsel][SW(j, j * 64 + f0)]     = *(const uint4*)qr;
    *(uint4*)&Qf[hsel][SW(j, j * 64 + f0 + 8)] = *(const uint4*)(qr + 8);
    if (tid < 256) {
      const unsigned short* kr =
          &qkvb[(size_t)(b * S_ + s0 + j) * QKVW + 1024 + g * 64 + f0];
      *(uint4*)&Kf[SW(j, j * 64 + f0)]     = *(const uint4*)kr;
      *(uint4*)&Kf[SW(j, j * 64 + f0 + 8)] = *(const uint4*)(kr + 8);
    } else {
      const unsigned short* vr =
          &qkvb[(size_t)(b * S_ + s0 + j) * QKVW + 1280 + g * 64 + f0];
      *(uint4*)&Ol[j][f0]     = *(const uint4*)vr;
      *(uint4*)&Ol[j][f0 + 8] = *(const uint4*)(vr + 8);
    }
  }
  __syncthreads();
  // V transpose in-LDS: Ol[s][d] -> Vl[d][s] (swizzled)
  {
    int d = tid >> 3, sq = (tid & 7) * 8;
    unsigned short tmp[8];
#pragma unroll
    for (int e = 0; e < 8; ++e) tmp[e] = Ol[sq + e][d];
    *(uint4*)&Vl[SW(d, d * 64 + sq)] = *(const uint4*)tmp;
  }
  // ---- inline exclusive prefix: Sl[dd][col..col+8) = sum_{cc<c} stc ----
  {
    int dd = tid >> 3, col = (tid & 7) * 8;
    const float* sb = stc + (size_t)(b * HKV_ + g) * NC * 4160 + dd * 64 + col;
    float p0[8], p1[8], p2[8], p3[8];
#pragma unroll
    for (int e = 0; e < 8; ++e) { p0[e] = 0.f; p1[e] = 0.f; p2[e] = 0.f; p3[e] = 0.f; }
    int cc = 0;
    for (; cc + 4 <= c; cc += 4) {
      const float* q0 = sb + (size_t)(cc + 0) * 4160;
      const float* q1 = sb + (size_t)(cc + 1) * 4160;
      const float* q2 = sb + (size_t)(cc + 2) * 4160;
      const float* q3 = sb + (size_t)(cc + 3) * 4160;
      float4 a0 = *(const float4*)q0, b0 = *(const float4*)(q0 + 4);
      float4 a1 = *(const float4*)q1, b1 = *(const float4*)(q1 + 4);
      float4 a2 = *(const float4*)q2, b2 = *(const float4*)(q2 + 4);
      float4 a3 = *(const float4*)q3, b3 = *(const float4*)(q3 + 4);
      p0[0] += a0.x; p0[1] += a0.y; p0[2] += a0.z; p0[3] += a0.w;
      p0[4] += b0.x; p0[5] += b0.y; p0[6] += b0.z; p0[7] += b0.w;
      p1[0] += a1.x; p1[1] += a1.y; p1[2] += a1.z; p1[3] += a1.w;
      p1[4] += b1.x; p1[5] += b1.y; p1[6] += b1.z; p1[7] += b1.w;
      p2[0] += a2.x; p2[1] += a2.y; p2[2] += a2.z; p2[3] += a2.w;
      p2[4] += b2.x; p2[5] += b2.y; p2[6] += b2.z; p2[7] += b2.w;
      p3[0] += a3.x; p3[1] += a3.y; p3[2] += a3.z; p3[3] += a3.w;
      p3[4] += b3.x; p3[5] += b3.y; p3[6] += b3.z; p3[7] += b3.w;
    }
    for (; cc < c; ++cc) {
      const float* q0 = sb + (size_t)cc * 4160;
      float4 a0 = *(const float4*)q0, b0 = *(const float4*)(q0 + 4);
      p0[0] += a0.x; p0[1] += a0.y; p0[2] += a0.z; p0[3] += a0.w;
      p0[4] += b0.x; p0[5] += b0.y; p0[6] += b0.z; p0[7] += b0.w;
    }
    unsigned short o[8];
#pragma unroll
    for (int e = 0; e < 8; ++e) o[e] = f2b(p0[e] + p1[e] + p2[e] + p3[e]);
    *(uint4*)&Sl[SW(dd, dd * 64 + col)] = *(const uint4*)o;
    // z prefix (row 64 of each chunk tile)
    if (tid < 64) {
      const float* zb = stc + (size_t)(b * HKV_ + g) * NC * 4160 + 64 * 64 + tid;
      float z0 = 0.f, z1 = 0.f, z2 = 0.f, z3 = 0.f;
      int c2 = 0;
      for (; c2 + 4 <= c; c2 += 4) {
        z0 += zb[(size_t)(c2 + 0) * 4160];
        z1 += zb[(size_t)(c2 + 1) * 4160];
        z2 += zb[(size_t)(c2 + 2) * 4160];
        z3 += zb[(size_t)(c2 + 3) * 4160];
      }
      for (; c2 < c; ++c2) z0 += zb[(size_t)c2 * 4160];
      zl[tid] = z0 + z1 + z2 + z3;
    }
  }
  __syncthreads();
  const int lr = lane & 15, lq = lane >> 4, lk = lq * 8;
  const int hh = wave >> 2, rw = (wave & 3) * 16;
  const f32x4 fzero = {0.f, 0.f, 0.f, 0.f};
  bf8 aQ[2];
#pragma unroll
  for (int kk = 0; kk < 2; ++kk)
    aQ[kk] = *(const bf8*)&Qf[hh][SW(rw + lr, (rw + lr) * 64 + kk * 32 + lk)];
  f32x4 sc[4];
#pragma unroll
  for (int nj = 0; nj < 4; ++nj) sc[nj] = fzero;
#pragma unroll
  for (int nj = 0; nj < 4; ++nj)
#pragma unroll
    for (int kk = 0; kk < 2; ++kk) {
      bf8 bk8 = *(const bf8*)&Kf[SW(nj * 16 + lr, (nj * 16 + lr) * 64 + kk * 32 + lk)];
      sc[nj] = MFMA_B16(aQ[kk], bk8, sc[nj]);
    }
#pragma unroll
  for (int nj = 0; nj < 4; ++nj)
#pragma unroll
    for (int r = 0; r < 4; ++r) {
      int i = rw + lq * 4 + r;
      int j = nj * 16 + lr;
      float v = (j <= i) ? sc[nj][r] : 0.f;
      P[hh][SW(i, i * 64 + j)] = f2b(v);
    }
  __syncthreads();
  {
    int hd = tid >> 8, t = tid & 255;
    int i = t >> 2, q = t & 3, f0 = q * 16;
    float s = 0.f;
#pragma unroll
    for (int e = 0; e < 16; ++e) s += b2f(P[hd][SW(i, i * 64 + f0 + e)]);
#pragma unroll
    for (int e = 0; e < 16; ++e) s += b2f(Qf[hd][SW(i, i * 64 + f0 + e)]) * zl[f0 + e];
    s += __shfl_xor(s, 1);
    s += __shfl_xor(s, 2);
    if (q == 0) den[hd][i] = s;
  }
  f32x4 oa[4];
#pragma unroll
  for (int nd = 0; nd < 4; ++nd) oa[nd] = fzero;
  bf8 aP[2];
#pragma unroll
  for (int kk = 0; kk < 2; ++kk)
    aP[kk] = *(const bf8*)&P[hh][SW(rw + lr, (rw + lr) * 64 + kk * 32 + lk)];
#pragma unroll
  for (int nd = 0; nd < 4; ++nd)
#pragma unroll
    for (int kk = 0; kk < 2; ++kk) {
      bf8 bS = *(const bf8*)&Sl[SW(nd * 16 + lr, (nd * 16 + lr) * 64 + kk * 32 + lk)];
      oa[nd] = MFMA_B16(aQ[kk], bS, oa[nd]);
      bf8 bV = *(const bf8*)&Vl[SW(nd * 16 + lr, (nd * 16 + lr) * 64 + kk * 32 + lk)];
      oa[nd] = MFMA_B16(aP[kk], bV, oa[nd]);
    }
  __syncthreads();
#pragma unroll
  for (int nd = 0; nd < 4; ++nd)
#pragma unroll
    for (int r = 0; r < 4; ++r) {
      int i = rw + lq * 4 + r;
      int dd = nd * 16 + lr;
      Ol[i][hh * 64 + dd] = f2b(oa[nd][r] / (den[hh][i] + 1e-6f));
    }
  __syncthreads();
  {
    int j = tid >> 3, u = tid & 7;
    unsigned short* orow = &ob[(size_t)(b * S_ + s0 + j) * D_ + hp * 128 + u * 16];
    *(uint4*)orow       = *(const uint4*)&Ol[j][u * 16];
    *(uint4*)(orow + 8) = *(const uint4*)&Ol[j][u * 16 + 8];
  }
}

// ------- residual + LayerNorm (bf16 x, bf16 o2) -------
__global__ __launch_bounds__(256) void k_ln(const unsigned short* __restrict__ xb,
                                            const unsigned short* __restrict__ o2,
                                            const float* __restrict__ gamma,
                                            const float* __restrict__ beta,
                                            float* __restrict__ out) {
  int row = blockIdx.x, tid = threadIdx.x;
  ushort4 xv = ((const ushort4*)(xb + (size_t)row * D_))[tid];
  ushort4 ov = ((const ushort4*)(o2 + (size_t)row * D_))[tid];
  float4 y;
  y.x = b2f(xv.x) + b2f(ov.x); y.y = b2f(xv.y) + b2f(ov.y);
  y.z = b2f(xv.z) + b2f(ov.z); y.w = b2f(xv.w) + b2f(ov.w);
  float s = y.x + y.y + y.z + y.w;
  float ss = y.x * y.x + y.y * y.y + y.z * y.z + y.w * y.w;
#pragma unroll
  for (int off = 32; off > 0; off >>= 1) {
    s += __shfl_down(s, off);
    ss += __shfl_down(ss, off);
  }
  __shared__ float red[8];
  int lane = tid & 63, wave = tid >> 6;
  if (lane == 0) { red[wave] = s; red[4 + wave] = ss; }
  __syncthreads();
  if (tid == 0) {
    red[0] = red[0] + red[1] + red[2] + red[3];
    red[4] = red[4] + red[5] + red[6] + red[7];
  }
  __syncthreads();
  float mu = red[0] * (1.f / D_);
  float var = red[4] * (1.f / D_) - mu * mu;
  float rs = rsqrtf(var + 1e-5f);
  float4 g4 = ((const float4*)gamma)[tid];
  float4 b4 = ((const float4*)beta)[tid];
  float4 o;
  o.x = (y.x - mu) * rs * g4.x + b4.x;
  o.y = (y.y - mu) * rs * g4.y + b4.y;
  o.z = (y.z - mu) * rs * g4.z + b4.z;
  o.w = (y.w - mu) * rs * g4.w + b4.w;
  ((float4*)(out + (size_t)row * D_))[tid] = o;
}

extern "C" void kernel_launch(void* const* d_in, const int* in_sizes, int n_in,
                              void* d_out, int out_size, void* d_ws, size_t ws_size,
                              hipStream_t stream) {
  const float* x     = (const float*)d_in[0];
  const float* Wq    = (const float*)d_in[1];
  const float* bq    = (const float*)d_in[2];
  const float* Wk    = (const float*)d_in[3];
  const float* bk    = (const float*)d_in[4];
  const float* Wv    = (const float*)d_in[5];
  const float* bv    = (const float*)d_in[6];
  const float* Wc    = (const float*)d_in[7];
  const float* We    = (const float*)d_in[8];
  const float* Wo    = (const float*)d_in[9];
  const float* bo    = (const float*)d_in[10];
  const float* gamma = (const float*)d_in[11];
  const float* beta  = (const float*)d_in[12];

  char* p = (char*)d_ws;
  size_t off = 0;
  auto carve = [&](size_t bytes) {
    void* r = p + off;
    off = (off + bytes + 255) & ~(size_t)255;
    return r;
  };
  unsigned short* xb     = (unsigned short*)carve((size_t)BS_ * D_ * 2);
  unsigned short* Wqkv_t = (unsigned short*)carve((size_t)QKVW * D_ * 2);
  unsigned short* Wo_t   = (unsigned short*)carve((size_t)D_ * D_ * 2);
  float*          biasq  = (float*)carve(QKVW * 4);
  unsigned short* qkvb   = (unsigned short*)carve((size_t)BS_ * QKVW * 2);
  float*          Wce    = (float*)carve(256 * 256 * 4);
  unsigned short* Wce_t  = (unsigned short*)carve(256 * 256 * 2);
  unsigned short* Wkv_b  = (unsigned short*)carve((size_t)2048 * 256 * 2);
  float*          stc    = (float*)carve((size_t)8 * NC * 65 * 64 * 4);
  unsigned short* obuf   = (unsigned short*)carve((size_t)BS_ * D_ * 2);
  unsigned short* o2     = (unsigned short*)carve((size_t)BS_ * D_ * 2);

  // P1: prep + self-contained Wce GEMM
  k_prep<<<3080, 256, 0, stream>>>(x, Wq, Wo, Wk, Wv, Wc, We,
                                   xb, Wqkv_t, Wo_t, Wkv_b, Wce, Wce_t);
  // P2: folded K/V weights into Wqkv_t rows [1024,1536) + bias fold
  k_fold<<<dim3(16, 5), 128, 0, stream>>>(Wce_t, Wkv_b, Wqkv_t, biasq,
                                          2048, 256, bq, bk, bv, Wce);
  // P3: fused QKV projection -> qkvb bf16 (Q,K pre-featted)
  k_gemm1<1><<<dim3(24, 32), 64, 0, stream>>>(xb, Wqkv_t, biasq, qkvb, QKVW, 1024);
  // P4: per-chunk KV sums
  k_vkv<<<dim3(NC, HKV_, B_), 256, 0, stream>>>(qkvb, stc);
  // P5: attention (inline prefix; 2 heads/block)
  k_attn<<<dim3(NC, H_ / 2, B_), 512, 0, stream>>>(qkvb, stc, obuf);
  // P6: output projection -> o2 bf16
  k_gemm1<0><<<dim3(16, 32), 64, 0, stream>>>(obuf, Wo_t, bo, o2, 1024, 1024);
  // P7: residual + LayerNorm (bf16 inputs)
  k_ln<<<BS_, 256, 0, stream>>>(xb, o2, gamma, beta, (float*)d_out);
}

// Round 11
// 87.187 us; speedup vs baseline: 1.7273x; 1.0045x over previous
//
#include <hip/hip_runtime.h>

#define D_ 1024
#define H_ 16
#define HKV_ 4
#define B_ 2
#define S_ 1024
#define BS_ (B_*S_)
#define QKVW 1536
#define QB 64
#define NC (S_/QB)

typedef short bf8 __attribute__((ext_vector_type(8)));
typedef float f32x4 __attribute__((ext_vector_type(4)));

#define MFMA_B16(a,b,c) __builtin_amdgcn_mfma_f32_16x16x32_bf16((a),(b),(c),0,0,0)

// async global->LDS, 16B per lane; LDS dest must be linear in lane order
#define GLOAD16(g, l) __builtin_amdgcn_global_load_lds( \
    (const __attribute__((address_space(1))) void*)(g), \
    (__attribute__((address_space(3))) void*)(l), 16, 0, 0)

// LDS XOR swizzle for [64][64] bf16 tiles: flips 16B-unit within 8-row stripe.
#define SW(row, idx) ((idx) ^ (((row) & 7) << 3))

__device__ __forceinline__ unsigned short f2b(float f) {
  unsigned int u = __float_as_uint(f);
  u += 0x7FFFu + ((u >> 16) & 1u);
  return (unsigned short)(u >> 16);
}
__device__ __forceinline__ float b2f(unsigned short h) {
  return __uint_as_float(((unsigned int)h) << 16);
}
__device__ __forceinline__ float feat(float x) { return x > 0.f ? x + 1.f : __expf(x); }

// ---------- helpers used by the fused prep kernel ----------
__device__ __forceinline__ void conv_body(const float* __restrict__ src,
                                          unsigned short* __restrict__ dst,
                                          int sub, int n4, int tid) {
  int i = sub * 256 + tid;
  if (i >= n4) return;
  float4 v = ((const float4*)src)[i];
  ushort4 o;
  o.x = f2b(v.x); o.y = f2b(v.y); o.z = f2b(v.z); o.w = f2b(v.w);
  ((ushort4*)dst)[i] = o;
}

__device__ __forceinline__ void tconv_body(const float* __restrict__ src,
                                           unsigned short* __restrict__ dst,
                                           int bx, int by, int ss, int ds,
                                           int tid, float (*tl)[65]) {
  int r0 = by * 64, c0 = bx * 64;
  int ty = tid >> 4, tx4 = (tid & 15) * 4;
#pragma unroll
  for (int rep = 0; rep < 4; ++rep) {
    int r = ty + rep * 16;
    float4 v = *(const float4*)&src[(size_t)(r0 + r) * ss + c0 + tx4];
    tl[r][tx4] = v.x; tl[r][tx4 + 1] = v.y; tl[r][tx4 + 2] = v.z; tl[r][tx4 + 3] = v.w;
  }
  __syncthreads();
#pragma unroll
  for (int rep = 0; rep < 4; ++rep) {
    int c = ty + rep * 16;
    ushort4 o;
    o.x = f2b(tl[tx4 + 0][c]); o.y = f2b(tl[tx4 + 1][c]);
    o.z = f2b(tl[tx4 + 2][c]); o.w = f2b(tl[tx4 + 3][c]);
    *(ushort4*)&dst[(size_t)(c0 + c) * ds + r0 + tx4] = o;
  }
}

// ---------- P1: all independent prep + self-contained Wce GEMM ----------
__global__ __launch_bounds__(256) void k_prep(const float* __restrict__ x,
                                              const float* __restrict__ Wq,
                                              const float* __restrict__ Wo,
                                              const float* __restrict__ Wk,
                                              const float* __restrict__ Wv,
                                              const float* __restrict__ Wc,
                                              const float* __restrict__ We,
                                              unsigned short* __restrict__ xb,
                                              unsigned short* __restrict__ Wqkv_t,
                                              unsigned short* __restrict__ Wo_t,
                                              unsigned short* __restrict__ Wkv_b,
                                              float* __restrict__ Wce,
                                              unsigned short* __restrict__ Wce_t) {
  __shared__ float tl[64][65];
  __shared__ __align__(16) unsigned short As[64][72];
  __shared__ __align__(16) unsigned short Bs[128][72];
  int blk = blockIdx.x, tid = threadIdx.x;
  if (blk < 2048) {
    conv_body(x, xb, blk, BS_ * D_ / 4, tid);
  } else if (blk < 2304) {
    conv_body(Wk, Wkv_b, blk - 2048, 1024 * 256 / 4, tid);
  } else if (blk < 2560) {
    conv_body(Wv, Wkv_b + 1024 * 256, blk - 2304, 1024 * 256 / 4, tid);
  } else if (blk < 2816) {
    int sb = blk - 2560;
    tconv_body(Wq, Wqkv_t, sb & 15, sb >> 4, 1024, 1024, tid, tl);
  } else if (blk < 3072) {
    int sb = blk - 2816;
    tconv_body(Wo, Wo_t, sb & 15, sb >> 4, 1024, 1024, tid, tl);
  } else {
    // ---- Wce[256,256] = Wc[256,64] @ We[64,256]; also Wce_t = Wce^T bf16 ----
    int sb = blk - 3072;
    int row0 = (sb >> 1) * 64, col0 = (sb & 1) * 128;
    {
      int r = tid >> 2, c0 = (tid & 3) * 16;
      const float* src = &Wc[(size_t)(row0 + r) * 64 + c0];
#pragma unroll
      for (int e = 0; e < 16; e += 4) {
        float4 v = *(const float4*)(src + e);
        As[r][c0 + e] = f2b(v.x); As[r][c0 + e + 1] = f2b(v.y);
        As[r][c0 + e + 2] = f2b(v.z); As[r][c0 + e + 3] = f2b(v.w);
      }
      int k = tid >> 2, cb = (tid & 3) * 32;
      const float* wsrc = &We[(size_t)k * 256 + col0 + cb];
#pragma unroll
      for (int e = 0; e < 32; e += 4) {
        float4 v = *(const float4*)(wsrc + e);
        Bs[cb + e][k] = f2b(v.x); Bs[cb + e + 1][k] = f2b(v.y);
        Bs[cb + e + 2][k] = f2b(v.z); Bs[cb + e + 3][k] = f2b(v.w);
      }
    }
    __syncthreads();
    const int lane = tid & 63, wave = tid >> 6;
    const int lr = lane & 15, lq = lane >> 4;
    const int wc0 = wave * 32;
    const f32x4 fzero = {0.f, 0.f, 0.f, 0.f};
    f32x4 acc[4][2];
#pragma unroll
    for (int i = 0; i < 4; ++i) { acc[i][0] = fzero; acc[i][1] = fzero; }
#pragma unroll
    for (int kk = 0; kk < 2; ++kk)
#pragma unroll
      for (int mi = 0; mi < 4; ++mi) {
        bf8 a = *(const bf8*)&As[mi * 16 + lr][kk * 32 + lq * 8];
#pragma unroll
        for (int ni = 0; ni < 2; ++ni) {
          bf8 bb = *(const bf8*)&Bs[wc0 + ni * 16 + lr][kk * 32 + lq * 8];
          acc[mi][ni] = MFMA_B16(a, bb, acc[mi][ni]);
        }
      }
#pragma unroll
    for (int mi = 0; mi < 4; ++mi)
#pragma unroll
      for (int ni = 0; ni < 2; ++ni) {
        int col = col0 + wc0 + ni * 16 + lr;
#pragma unroll
        for (int r = 0; r < 4; ++r) {
          int row = row0 + mi * 16 + lq * 4 + r;
          float v = acc[mi][ni][r];
          Wce[(size_t)row * 256 + col] = v;
          Wce_t[(size_t)col * 256 + row] = f2b(v);
        }
      }
  }
}

// ---------- 1-wave 64x64 bt-GEMM: no barriers, dbuf LDS, BK=64, counted vmcnt ----
template<int MODE>
__global__ __launch_bounds__(64) void k_gemm1(const unsigned short* __restrict__ A,
                                              const unsigned short* __restrict__ Bt,
                                              const float* __restrict__ bias,
                                              unsigned short* __restrict__ C,
                                              int N, int K) {
  __shared__ __align__(16) unsigned short As[2][64 * 64];
  __shared__ __align__(16) unsigned short Bs[2][64 * 64];
  const int lane = threadIdx.x;
  const int row0 = blockIdx.y * 64, col0 = blockIdx.x * 64;
  const int lr = lane & 15, lq = lane >> 4;
  const int rsub = lane >> 3, sj = lane & 7;
  const int js = sj ^ rsub;            // swizzled chunk, loop-invariant
  const f32x4 fzero = {0.f, 0.f, 0.f, 0.f};
  f32x4 acc[4][4];
#pragma unroll
  for (int i = 0; i < 4; ++i)
#pragma unroll
    for (int j = 0; j < 4; ++j) acc[i][j] = fzero;

#define STAGE64(pb, k0)                                                        \
  {                                                                            \
    _Pragma("unroll")                                                          \
    for (int i = 0; i < 8; ++i)                                                \
      GLOAD16(&A[(size_t)(row0 + i * 8 + rsub) * K + (k0) + js * 8],           \
              &As[pb][(i * 512 + lane * 8)]);                                  \
    _Pragma("unroll")                                                          \
    for (int i = 0; i < 8; ++i)                                                \
      GLOAD16(&Bt[(size_t)(col0 + i * 8 + rsub) * K + (k0) + js * 8],          \
              &Bs[pb][(i * 512 + lane * 8)]);                                  \
  }

  STAGE64(0, 0);
  int cur = 0;
  for (int k0 = 0; k0 < K; k0 += 64) {
    if (k0 + 64 < K) {
      STAGE64(cur ^ 1, k0 + 64);
      asm volatile("s_waitcnt vmcnt(16)" ::: "memory");
    } else {
      asm volatile("s_waitcnt vmcnt(0)" ::: "memory");
    }
    __builtin_amdgcn_sched_barrier(0);
    bf8 af[2][4], bfr[2][4];
#pragma unroll
    for (int kk = 0; kk < 2; ++kk)
#pragma unroll
      for (int mi = 0; mi < 4; ++mi) {
        int ch = (kk * 4 + lq) ^ (lr & 7);
        af[kk][mi]  = *(const bf8*)&As[cur][(mi * 16 + lr) * 64 + ch * 8];
        bfr[kk][mi] = *(const bf8*)&Bs[cur][(mi * 16 + lr) * 64 + ch * 8];
      }
#pragma unroll
    for (int kk = 0; kk < 2; ++kk)
#pragma unroll
      for (int mi = 0; mi < 4; ++mi)
#pragma unroll
        for (int ni = 0; ni < 4; ++ni)
          acc[mi][ni] = MFMA_B16(af[kk][mi], bfr[kk][ni], acc[mi][ni]);
    cur ^= 1;
  }
#undef STAGE64
#pragma unroll
  for (int ni = 0; ni < 4; ++ni) {
    int col = col0 + ni * 16 + lr;
    float bv = bias[col];
#pragma unroll
    for (int mi = 0; mi < 4; ++mi)
#pragma unroll
      for (int r = 0; r < 4; ++r) {
        int row = row0 + mi * 16 + lq * 4 + r;
        float v = acc[mi][ni][r] + bv;
        if (MODE == 1 && col < 1280) v = feat(v);
        C[(size_t)row * N + col] = f2b(v);
      }
  }
}

// ---------- weight-fold bt-GEMM (P3), 64x128 tile, 2 waves ----------
__global__ __launch_bounds__(128) void k_fold(const unsigned short* __restrict__ A,
                                              const unsigned short* __restrict__ Bt,
                                              unsigned short* __restrict__ C,
                                              float* __restrict__ biasq,
                                              int N, int K,
                                              const float* __restrict__ fbq,
                                              const float* __restrict__ fbk,
                                              const float* __restrict__ fbv,
                                              const float* __restrict__ fWce) {
  if (blockIdx.y == 4) {
    int t = blockIdx.x * 128 + threadIdx.x;
    if (t >= QKVW) return;
    if (t < 1024) { biasq[t] = fbq[t]; return; }
    const float* b = (t < 1280) ? fbk : fbv;
    int n = (t < 1280) ? (t - 1024) : (t - 1280);
    float s = 0.f;
    for (int j = 0; j < 256; ++j) s += b[j] * fWce[j * 256 + n];
    biasq[t] = s;
    return;
  }
  __shared__ __align__(16) unsigned short As[64 * 32];
  __shared__ __align__(16) unsigned short Bs[128 * 32];
  const int tid = threadIdx.x;
  const int lane = tid & 63, wave = tid >> 6;
  const int row0 = blockIdx.y * 64, col0 = blockIdx.x * 128;
  const f32x4 fzero = {0.f, 0.f, 0.f, 0.f};
  f32x4 acc[4][4];
#pragma unroll
  for (int i = 0; i < 4; ++i)
#pragma unroll
    for (int j = 0; j < 4; ++j) acc[i][j] = fzero;
  const int lr = lane & 15, lq = lane >> 4, lk = lq * 8;
  for (int k0 = 0; k0 < K; k0 += 32) {
#pragma unroll
    for (int i = 0; i < 2; ++i) {
      int e = (tid + i * 128) * 8;
      int r = e >> 5, c = e & 31;
      GLOAD16(&A[(size_t)(row0 + r) * K + k0 + c], &As[e]);
    }
#pragma unroll
    for (int i = 0; i < 4; ++i) {
      int e = (tid + i * 128) * 8;
      int r = e >> 5, c = e & 31;
      GLOAD16(&Bt[(size_t)(col0 + r) * K + k0 + c], &Bs[e]);
    }
    __syncthreads();
    bf8 af[4], bfr[4];
#pragma unroll
    for (int mi = 0; mi < 4; ++mi)
      af[mi] = *(const bf8*)&As[(mi * 16 + lr) * 32 + lk];
#pragma unroll
    for (int ni = 0; ni < 4; ++ni)
      bfr[ni] = *(const bf8*)&Bs[(wave * 64 + ni * 16 + lr) * 32 + lk];
#pragma unroll
    for (int mi = 0; mi < 4; ++mi)
#pragma unroll
      for (int ni = 0; ni < 4; ++ni)
        acc[mi][ni] = MFMA_B16(af[mi], bfr[ni], acc[mi][ni]);
    __syncthreads();
  }
#pragma unroll
  for (int mi = 0; mi < 4; ++mi)
#pragma unroll
    for (int ni = 0; ni < 4; ++ni) {
      int col = col0 + wave * 64 + ni * 16 + lr;
#pragma unroll
      for (int r = 0; r < 4; ++r) {
        int row = row0 + mi * 16 + lq * 4 + r;
        int sec = col >> 10, cc = col & 1023;
        C[(size_t)(1024 + sec * 256 + row) * 1024 + cc] = f2b(acc[mi][ni][r]);
      }
    }
}

// ---------- per-chunk KV sums only ----------
__global__ __launch_bounds__(256) void k_vkv(const unsigned short* __restrict__ qkvb,
                                             float* __restrict__ stc) {
  __shared__ unsigned short tl[64][72];   // V staging (raw bf16), [s][d]
  __shared__ float Kf[64 * 64];
  int c = blockIdx.x, g = blockIdx.y, b = blockIdx.z;
  int tid = threadIdx.x;
  int s0 = c * QB;
  {
    int j = tid >> 2, f0 = (tid & 3) * 16;
    const unsigned short* kr = &qkvb[(size_t)(b * S_ + s0 + j) * QKVW + 1024 + g * 64 + f0];
    const unsigned short* vr = &qkvb[(size_t)(b * S_ + s0 + j) * QKVW + 1280 + g * 64 + f0];
    uint4 k0_ = *(const uint4*)kr;
    uint4 k1_ = *(const uint4*)(kr + 8);
    const unsigned short* ks = (const unsigned short*)&k0_;
#pragma unroll
    for (int e = 0; e < 8; ++e) Kf[j * 64 + f0 + e] = b2f(ks[e]);
    ks = (const unsigned short*)&k1_;
#pragma unroll
    for (int e = 0; e < 8; ++e) Kf[j * 64 + f0 + 8 + e] = b2f(ks[e]);
    *(uint4*)&tl[j][f0] = *(const uint4*)vr;
    *(uint4*)&tl[j][f0 + 8] = *(const uint4*)(vr + 8);
  }
  __syncthreads();
  int d = tid >> 2, f0 = (tid & 3) * 16;
  float acc[16];
#pragma unroll
  for (int e = 0; e < 16; ++e) acc[e] = 0.f;
#pragma unroll 4
  for (int j = 0; j < QB; ++j) {
    float vv = b2f(tl[j][d]);
    const float* kfr = &Kf[j * 64 + f0];
#pragma unroll
    for (int e = 0; e < 16; ++e) acc[e] += vv * kfr[e];
  }
  size_t base = ((size_t)((b * HKV_ + g) * NC + c) * 65 + d) * 64 + f0;
#pragma unroll
  for (int e = 0; e < 16; ++e) stc[base + e] = acc[e];
  if (tid < 64) {
    float z = 0.f;
    for (int j = 0; j < QB; ++j) z += Kf[j * 64 + tid];
    stc[((size_t)((b * HKV_ + g) * NC + c) * 65 + 64) * 64 + tid] = z;
  }
}

// ---------- per-(chunk, head-pair) attention + inline exclusive prefix ----------
// R11: Qf LDS removed (Q fragments direct from global; Qf.z term via register
// dot + shfl into qz[]); Ol removed (P buffer reused for V staging and O
// staging). LDS 74.5 -> 41.3 KB => 3 blocks/CU.
__global__ __launch_bounds__(512) void k_attn(const unsigned short* __restrict__ qkvb,
                                              const float* __restrict__ stc,
                                              unsigned short* __restrict__ ob) {
  __shared__ __align__(16) unsigned short Kf[64 * 64];
  __shared__ __align__(16) unsigned short Vl[64 * 64];
  __shared__ __align__(16) unsigned short Sl[64 * 64];
  __shared__ __align__(16) unsigned short P[2][64 * 64];  // V scratch / scores / O staging
  __shared__ float zl[64];
  __shared__ float qz[2][64];
  __shared__ float den[2][64];
  int c = blockIdx.x, hp = blockIdx.y, b = blockIdx.z;
  int g = hp >> 1;
  int tid = threadIdx.x, lane = tid & 63, wave = tid >> 6;
  int s0 = c * QB;
  const int lr = lane & 15, lq = lane >> 4, lk = lq * 8;
  const int hh = wave >> 2, rw = (wave & 3) * 16;
  unsigned short* Pv = &P[0][0];   // V-row scratch, stride 72 (4608 <= 8192)

  // ---- phase A: load K -> Kf, V rows -> Pv; inline prefix -> Sl, zl ----
  {
    int t = tid & 255;
    int j = t >> 2, f0 = (t & 3) * 16;
    if (tid < 256) {
      const unsigned short* kr =
          &qkvb[(size_t)(b * S_ + s0 + j) * QKVW + 1024 + g * 64 + f0];
      *(uint4*)&Kf[SW(j, j * 64 + f0)]     = *(const uint4*)kr;
      *(uint4*)&Kf[SW(j, j * 64 + f0 + 8)] = *(const uint4*)(kr + 8);
    } else {
      const unsigned short* vr =
          &qkvb[(size_t)(b * S_ + s0 + j) * QKVW + 1280 + g * 64 + f0];
      *(uint4*)&Pv[j * 72 + f0]     = *(const uint4*)vr;
      *(uint4*)&Pv[j * 72 + f0 + 8] = *(const uint4*)(vr + 8);
    }
  }
  {
    int dd = tid >> 3, col = (tid & 7) * 8;
    const float* sb = stc + (size_t)(b * HKV_ + g) * NC * 4160 + dd * 64 + col;
    float p0[8], p1[8], p2[8], p3[8];
#pragma unroll
    for (int e = 0; e < 8; ++e) { p0[e] = 0.f; p1[e] = 0.f; p2[e] = 0.f; p3[e] = 0.f; }
    int cc = 0;
    for (; cc + 4 <= c; cc += 4) {
      const float* q0 = sb + (size_t)(cc + 0) * 4160;
      const float* q1 = sb + (size_t)(cc + 1) * 4160;
      const float* q2 = sb + (size_t)(cc + 2) * 4160;
      const float* q3 = sb + (size_t)(cc + 3) * 4160;
      float4 a0 = *(const float4*)q0, b0 = *(const float4*)(q0 + 4);
      float4 a1 = *(const float4*)q1, b1 = *(const float4*)(q1 + 4);
      float4 a2 = *(const float4*)q2, b2 = *(const float4*)(q2 + 4);
      float4 a3 = *(const float4*)q3, b3 = *(const float4*)(q3 + 4);
      p0[0] += a0.x; p0[1] += a0.y; p0[2] += a0.z; p0[3] += a0.w;
      p0[4] += b0.x; p0[5] += b0.y; p0[6] += b0.z; p0[7] += b0.w;
      p1[0] += a1.x; p1[1] += a1.y; p1[2] += a1.z; p1[3] += a1.w;
      p1[4] += b1.x; p1[5] += b1.y; p1[6] += b1.z; p1[7] += b1.w;
      p2[0] += a2.x; p2[1] += a2.y; p2[2] += a2.z; p2[3] += a2.w;
      p2[4] += b2.x; p2[5] += b2.y; p2[6] += b2.z; p2[7] += b2.w;
      p3[0] += a3.x; p3[1] += a3.y; p3[2] += a3.z; p3[3] += a3.w;
      p3[4] += b3.x; p3[5] += b3.y; p3[6] += b3.z; p3[7] += b3.w;
    }
    for (; cc < c; ++cc) {
      const float* q0 = sb + (size_t)cc * 4160;
      float4 a0 = *(const float4*)q0, b0 = *(const float4*)(q0 + 4);
      p0[0] += a0.x; p0[1] += a0.y; p0[2] += a0.z; p0[3] += a0.w;
      p0[4] += b0.x; p0[5] += b0.y; p0[6] += b0.z; p0[7] += b0.w;
    }
    unsigned short o[8];
#pragma unroll
    for (int e = 0; e < 8; ++e) o[e] = f2b(p0[e] + p1[e] + p2[e] + p3[e]);
    *(uint4*)&Sl[SW(dd, dd * 64 + col)] = *(const uint4*)o;
    if (tid < 64) {
      const float* zb = stc + (size_t)(b * HKV_ + g) * NC * 4160 + 64 * 64 + tid;
      float z0 = 0.f, z1 = 0.f, z2 = 0.f, z3 = 0.f;
      int c2 = 0;
      for (; c2 + 4 <= c; c2 += 4) {
        z0 += zb[(size_t)(c2 + 0) * 4160];
        z1 += zb[(size_t)(c2 + 1) * 4160];
        z2 += zb[(size_t)(c2 + 2) * 4160];
        z3 += zb[(size_t)(c2 + 3) * 4160];
      }
      for (; c2 < c; ++c2) z0 += zb[(size_t)c2 * 4160];
      zl[tid] = z0 + z1 + z2 + z3;
    }
  }
  // Q fragments direct from global (L2-resident qkvb)
  bf8 aQ[2];
  {
    const unsigned short* qr =
        &qkvb[(size_t)(b * S_ + s0 + rw + lr) * QKVW + (hp * 2 + hh) * 64];
    aQ[0] = *(const bf8*)(qr + lk);
    aQ[1] = *(const bf8*)(qr + 32 + lk);
  }
  __syncthreads();
  // ---- phase B: V transpose Pv -> Vl; qz = Q-row . z (register dot) ----
  {
    int d = tid >> 3, sq = (tid & 7) * 8;
    unsigned short tmp[8];
#pragma unroll
    for (int e = 0; e < 8; ++e) tmp[e] = Pv[(sq + e) * 72 + d];
    *(uint4*)&Vl[SW(d, d * 64 + sq)] = *(const uint4*)tmp;
  }
  {
    float qdot = 0.f;
#pragma unroll
    for (int kk = 0; kk < 2; ++kk)
#pragma unroll
      for (int e = 0; e < 8; ++e)
        qdot += b2f((unsigned short)aQ[kk][e]) * zl[kk * 32 + lq * 8 + e];
    qdot += __shfl_xor(qdot, 16);
    qdot += __shfl_xor(qdot, 32);
    if (lq == 0) qz[hh][rw + lr] = qdot;
  }
  __syncthreads();
  // ---- phase C: QK^T, causal mask, write scores into P ----
  const f32x4 fzero = {0.f, 0.f, 0.f, 0.f};
  f32x4 sc[4];
#pragma unroll
  for (int nj = 0; nj < 4; ++nj) sc[nj] = fzero;
#pragma unroll
  for (int nj = 0; nj < 4; ++nj)
#pragma unroll
    for (int kk = 0; kk < 2; ++kk) {
      bf8 bk8 = *(const bf8*)&Kf[SW(nj * 16 + lr, (nj * 16 + lr) * 64 + kk * 32 + lk)];
      sc[nj] = MFMA_B16(aQ[kk], bk8, sc[nj]);
    }
#pragma unroll
  for (int nj = 0; nj < 4; ++nj)
#pragma unroll
    for (int r = 0; r < 4; ++r) {
      int i = rw + lq * 4 + r;
      int j = nj * 16 + lr;
      float v = (j <= i) ? sc[nj][r] : 0.f;
      P[hh][SW(i, i * 64 + j)] = f2b(v);
    }
  __syncthreads();
  // ---- phase D: den = rowsum(P) + qz; PV + QS MFMAs ----
  {
    int hd = tid >> 8, t = tid & 255;
    int i = t >> 2, q = t & 3, f0 = q * 16;
    float s = 0.f;
#pragma unroll
    for (int e = 0; e < 16; ++e) s += b2f(P[hd][SW(i, i * 64 + f0 + e)]);
    s += __shfl_xor(s, 1);
    s += __shfl_xor(s, 2);
    if (q == 0) den[hd][i] = s + qz[hd][i];
  }
  f32x4 oa[4];
#pragma unroll
  for (int nd = 0; nd < 4; ++nd) oa[nd] = fzero;
  bf8 aP[2];
#pragma unroll
  for (int kk = 0; kk < 2; ++kk)
    aP[kk] = *(const bf8*)&P[hh][SW(rw + lr, (rw + lr) * 64 + kk * 32 + lk)];
#pragma unroll
  for (int nd = 0; nd < 4; ++nd)
#pragma unroll
    for (int kk = 0; kk < 2; ++kk) {
      bf8 bS = *(const bf8*)&Sl[SW(nd * 16 + lr, (nd * 16 + lr) * 64 + kk * 32 + lk)];
      oa[nd] = MFMA_B16(aQ[kk], bS, oa[nd]);
      bf8 bV = *(const bf8*)&Vl[SW(nd * 16 + lr, (nd * 16 + lr) * 64 + kk * 32 + lk)];
      oa[nd] = MFMA_B16(aP[kk], bV, oa[nd]);
    }
  __syncthreads();   // all P reads done; den visible
  // ---- phase E: O staging into P (flat [64][128]) ----
#pragma unroll
  for (int nd = 0; nd < 4; ++nd)
#pragma unroll
    for (int r = 0; r < 4; ++r) {
      int i = rw + lq * 4 + r;
      int dd = nd * 16 + lr;
      P[0][0] = P[0][0];  // no-op to keep P referenced (optimizer-safe)
      (&P[0][0])[i * 128 + hh * 64 + dd] = f2b(oa[nd][r] / (den[hh][i] + 1e-6f));
    }
  __syncthreads();
  // ---- phase F: coalesced store, 64 rows x 128 cols ----
  {
    int j = tid >> 3, u = tid & 7;
    unsigned short* orow = &ob[(size_t)(b * S_ + s0 + j) * D_ + hp * 128 + u * 16];
    *(uint4*)orow       = *(const uint4*)&(&P[0][0])[j * 128 + u * 16];
    *(uint4*)(orow + 8) = *(const uint4*)&(&P[0][0])[j * 128 + u * 16 + 8];
  }
}

// ------- residual + LayerNorm (bf16 x, bf16 o2) -------
__global__ __launch_bounds__(256) void k_ln(const unsigned short* __restrict__ xb,
                                            const unsigned short* __restrict__ o2,
                                            const float* __restrict__ gamma,
                                            const float* __restrict__ beta,
                                            float* __restrict__ out) {
  int row = blockIdx.x, tid = threadIdx.x;
  ushort4 xv = ((const ushort4*)(xb + (size_t)row * D_))[tid];
  ushort4 ov = ((const ushort4*)(o2 + (size_t)row * D_))[tid];
  float4 y;
  y.x = b2f(xv.x) + b2f(ov.x); y.y = b2f(xv.y) + b2f(ov.y);
  y.z = b2f(xv.z) + b2f(ov.z); y.w = b2f(xv.w) + b2f(ov.w);
  float s = y.x + y.y + y.z + y.w;
  float ss = y.x * y.x + y.y * y.y + y.z * y.z + y.w * y.w;
#pragma unroll
  for (int off = 32; off > 0; off >>= 1) {
    s += __shfl_down(s, off);
    ss += __shfl_down(ss, off);
  }
  __shared__ float red[8];
  int lane = tid & 63, wave = tid >> 6;
  if (lane == 0) { red[wave] = s; red[4 + wave] = ss; }
  __syncthreads();
  if (tid == 0) {
    red[0] = red[0] + red[1] + red[2] + red[3];
    red[4] = red[4] + red[5] + red[6] + red[7];
  }
  __syncthreads();
  float mu = red[0] * (1.f / D_);
  float var = red[4] * (1.f / D_) - mu * mu;
  float rs = rsqrtf(var + 1e-5f);
  float4 g4 = ((const float4*)gamma)[tid];
  float4 b4 = ((const float4*)beta)[tid];
  float4 o;
  o.x = (y.x - mu) * rs * g4.x + b4.x;
  o.y = (y.y - mu) * rs * g4.y + b4.y;
  o.z = (y.z - mu) * rs * g4.z + b4.z;
  o.w = (y.w - mu) * rs * g4.w + b4.w;
  ((float4*)(out + (size_t)row * D_))[tid] = o;
}

extern "C" void kernel_launch(void* const* d_in, const int* in_sizes, int n_in,
                              void* d_out, int out_size, void* d_ws, size_t ws_size,
                              hipStream_t stream) {
  const float* x     = (const float*)d_in[0];
  const float* Wq    = (const float*)d_in[1];
  const float* bq    = (const float*)d_in[2];
  const float* Wk    = (const float*)d_in[3];
  const float* bk    = (const float*)d_in[4];
  const float* Wv    = (const float*)d_in[5];
  const float* bv    = (const float*)d_in[6];
  const float* Wc    = (const float*)d_in[7];
  const float* We    = (const float*)d_in[8];
  const float* Wo    = (const float*)d_in[9];
  const float* bo    = (const float*)d_in[10];
  const float* gamma = (const float*)d_in[11];
  const float* beta  = (const float*)d_in[12];

  char* p = (char*)d_ws;
  size_t off = 0;
  auto carve = [&](size_t bytes) {
    void* r = p + off;
    off = (off + bytes + 255) & ~(size_t)255;
    return r;
  };
  unsigned short* xb     = (unsigned short*)carve((size_t)BS_ * D_ * 2);
  unsigned short* Wqkv_t = (unsigned short*)carve((size_t)QKVW * D_ * 2);
  unsigned short* Wo_t   = (unsigned short*)carve((size_t)D_ * D_ * 2);
  float*          biasq  = (float*)carve(QKVW * 4);
  unsigned short* qkvb   = (unsigned short*)carve((size_t)BS_ * QKVW * 2);
  float*          Wce    = (float*)carve(256 * 256 * 4);
  unsigned short* Wce_t  = (unsigned short*)carve(256 * 256 * 2);
  unsigned short* Wkv_b  = (unsigned short*)carve((size_t)2048 * 256 * 2);
  float*          stc    = (float*)carve((size_t)8 * NC * 65 * 64 * 4);
  unsigned short* obuf   = (unsigned short*)carve((size_t)BS_ * D_ * 2);
  unsigned short* o2     = (unsigned short*)carve((size_t)BS_ * D_ * 2);

  // P1: prep + self-contained Wce GEMM
  k_prep<<<3080, 256, 0, stream>>>(x, Wq, Wo, Wk, Wv, Wc, We,
                                   xb, Wqkv_t, Wo_t, Wkv_b, Wce, Wce_t);
  // P2: folded K/V weights into Wqkv_t rows [1024,1536) + bias fold
  k_fold<<<dim3(16, 5), 128, 0, stream>>>(Wce_t, Wkv_b, Wqkv_t, biasq,
                                          2048, 256, bq, bk, bv, Wce);
  // P3: fused QKV projection -> qkvb bf16 (Q,K pre-featted)
  k_gemm1<1><<<dim3(24, 32), 64, 0, stream>>>(xb, Wqkv_t, biasq, qkvb, QKVW, 1024);
  // P4: per-chunk KV sums
  k_vkv<<<dim3(NC, HKV_, B_), 256, 0, stream>>>(qkvb, stc);
  // P5: attention (inline prefix; 2 heads/block; 3 blocks/CU)
  k_attn<<<dim3(NC, H_ / 2, B_), 512, 0, stream>>>(qkvb, stc, obuf);
  // P6: output projection -> o2 bf16
  k_gemm1<0><<<dim3(16, 32), 64, 0, stream>>>(obuf, Wo_t, bo, o2, 1024, 1024);
  // P7: residual + LayerNorm (bf16 inputs)
  k_ln<<<BS_, 256, 0, stream>>>(xb, o2, gamma, beta, (float*)d_out);
}

// Round 12
// 81.303 us; speedup vs baseline: 1.8523x; 1.0724x over previous
//
#include <hip/hip_runtime.h>

#define D_ 1024
#define H_ 16
#define HKV_ 4
#define B_ 2
#define S_ 1024
#define BS_ (B_*S_)
#define QKVW 1536
#define QB 64
#define NC (S_/QB)

typedef short bf8 __attribute__((ext_vector_type(8)));
typedef float f32x4 __attribute__((ext_vector_type(4)));

#define MFMA_B16(a,b,c) __builtin_amdgcn_mfma_f32_16x16x32_bf16((a),(b),(c),0,0,0)

// async global->LDS, 16B per lane; LDS dest must be linear in lane order
#define GLOAD16(g, l) __builtin_amdgcn_global_load_lds( \
    (const __attribute__((address_space(1))) void*)(g), \
    (__attribute__((address_space(3))) void*)(l), 16, 0, 0)

// LDS XOR swizzle for [64][64] bf16 tiles: flips 16B-unit within 8-row stripe.
#define SW(row, idx) ((idx) ^ (((row) & 7) << 3))

__device__ __forceinline__ unsigned short f2b(float f) {
  unsigned int u = __float_as_uint(f);
  u += 0x7FFFu + ((u >> 16) & 1u);
  return (unsigned short)(u >> 16);
}
__device__ __forceinline__ float b2f(unsigned short h) {
  return __uint_as_float(((unsigned int)h) << 16);
}
__device__ __forceinline__ float feat(float x) { return x > 0.f ? x + 1.f : __expf(x); }

// ---------- helpers used by the fused prep kernel ----------
__device__ __forceinline__ void conv_body(const float* __restrict__ src,
                                          unsigned short* __restrict__ dst,
                                          int sub, int n4, int tid) {
  int i = sub * 256 + tid;
  if (i >= n4) return;
  float4 v = ((const float4*)src)[i];
  ushort4 o;
  o.x = f2b(v.x); o.y = f2b(v.y); o.z = f2b(v.z); o.w = f2b(v.w);
  ((ushort4*)dst)[i] = o;
}

__device__ __forceinline__ void tconv_body(const float* __restrict__ src,
                                           unsigned short* __restrict__ dst,
                                           int bx, int by, int ss, int ds,
                                           int tid, float (*tl)[65]) {
  int r0 = by * 64, c0 = bx * 64;
  int ty = tid >> 4, tx4 = (tid & 15) * 4;
#pragma unroll
  for (int rep = 0; rep < 4; ++rep) {
    int r = ty + rep * 16;
    float4 v = *(const float4*)&src[(size_t)(r0 + r) * ss + c0 + tx4];
    tl[r][tx4] = v.x; tl[r][tx4 + 1] = v.y; tl[r][tx4 + 2] = v.z; tl[r][tx4 + 3] = v.w;
  }
  __syncthreads();
#pragma unroll
  for (int rep = 0; rep < 4; ++rep) {
    int c = ty + rep * 16;
    ushort4 o;
    o.x = f2b(tl[tx4 + 0][c]); o.y = f2b(tl[tx4 + 1][c]);
    o.z = f2b(tl[tx4 + 2][c]); o.w = f2b(tl[tx4 + 3][c]);
    *(ushort4*)&dst[(size_t)(c0 + c) * ds + r0 + tx4] = o;
  }
}

// ---------- P1: prep + self-contained KV weight-fold + bias fold ----------
// blocks 0..2047:    x f32->bf16
// blocks 2048..2303: Wq tconv   2304..2559: Wo tconv
// blocks 2560..2623: fold: Wqkv_t rows [1024,1536) = (Wce^T @ Wkv^T) bf16,
//                    recomputing the needed Wce^T slice from Wc/We f32 per block
// block  2624:       bias fold (bk@Wc)@We, (bv@Wc)@We
// block  2625:       bq copy
__global__ __launch_bounds__(256) void k_prep(const float* __restrict__ x,
                                              const float* __restrict__ Wq,
                                              const float* __restrict__ Wo,
                                              const float* __restrict__ Wk,
                                              const float* __restrict__ Wv,
                                              const float* __restrict__ Wc,
                                              const float* __restrict__ We,
                                              const float* __restrict__ bq,
                                              const float* __restrict__ bk,
                                              const float* __restrict__ bv,
                                              unsigned short* __restrict__ xb,
                                              unsigned short* __restrict__ Wqkv_t,
                                              unsigned short* __restrict__ Wo_t,
                                              float* __restrict__ biasq) {
  __shared__ __align__(16) unsigned char smem[46080];
  int blk = blockIdx.x, tid = threadIdx.x;
  if (blk < 2048) {
    conv_body(x, xb, blk, BS_ * D_ / 4, tid);
  } else if (blk < 2304) {
    int sb = blk - 2048;
    tconv_body(Wq, Wqkv_t, sb & 15, sb >> 4, 1024, 1024, tid, (float(*)[65])smem);
  } else if (blk < 2560) {
    int sb = blk - 2304;
    tconv_body(Wo, Wo_t, sb & 15, sb >> 4, 1024, 1024, tid, (float(*)[65])smem);
  } else if (blk < 2624) {
    // ---- fold block: rows [row0,row0+64) x cols [col0,col0+128) ----
    int sb = blk - 2560;
    int bx = sb & 15, by = sb >> 4;
    int col0 = bx * 128, row0 = by * 64;
    unsigned short (*Aw)[72] = (unsigned short(*)[72])smem;                 // [64][72]
    unsigned short (*Bc)[72] = (unsigned short(*)[72])(smem + 64 * 72 * 2); // [256][72]
    // phase 1 load: Aw[r][j] = bf16(We[j][row0+r]); Bc[k][j] = bf16(Wc[k][j])
    {
      int j = tid >> 2, c4 = (tid & 3) * 16;
      const float* src = &We[(size_t)j * 256 + row0 + c4];
#pragma unroll
      for (int e = 0; e < 16; e += 4) {
        float4 v = *(const float4*)(src + e);
        Aw[c4 + e + 0][j] = f2b(v.x); Aw[c4 + e + 1][j] = f2b(v.y);
        Aw[c4 + e + 2][j] = f2b(v.z); Aw[c4 + e + 3][j] = f2b(v.w);
      }
      const float* wsrc = &Wc[(size_t)tid * 64];
#pragma unroll
      for (int e = 0; e < 64; e += 4) {
        float4 v = *(const float4*)(wsrc + e);
        Bc[tid][e + 0] = f2b(v.x); Bc[tid][e + 1] = f2b(v.y);
        Bc[tid][e + 2] = f2b(v.z); Bc[tid][e + 3] = f2b(v.w);
      }
    }
    __syncthreads();
    // phase 1 MFMA: T[r][k] = sum_j Aw[r][j]*Bc[k][j]; wave w: k in [w*64,w*64+64)
    const int lane = tid & 63, wave = tid >> 6;
    const int lr = lane & 15, lq = lane >> 4;
    const f32x4 fzero = {0.f, 0.f, 0.f, 0.f};
    f32x4 tacc[4][4];
#pragma unroll
    for (int i = 0; i < 4; ++i)
#pragma unroll
      for (int j = 0; j < 4; ++j) tacc[i][j] = fzero;
#pragma unroll
    for (int kk = 0; kk < 2; ++kk)
#pragma unroll
      for (int mi = 0; mi < 4; ++mi) {
        bf8 a = *(const bf8*)&Aw[mi * 16 + lr][kk * 32 + lq * 8];
#pragma unroll
        for (int ni = 0; ni < 4; ++ni) {
          bf8 bb = *(const bf8*)&Bc[wave * 64 + ni * 16 + lr][kk * 32 + lq * 8];
          tacc[mi][ni] = MFMA_B16(a, bb, tacc[mi][ni]);
        }
      }
    __syncthreads();
    // write T[64][264] bf16 over the (now dead) Aw/Bc region
    unsigned short (*T)[264] = (unsigned short(*)[264])smem;
#pragma unroll
    for (int mi = 0; mi < 4; ++mi)
#pragma unroll
      for (int ni = 0; ni < 4; ++ni) {
        int k = wave * 64 + ni * 16 + lr;
#pragma unroll
        for (int r = 0; r < 4; ++r)
          T[mi * 16 + lq * 4 + r][k] = f2b(tacc[mi][ni][r]);
      }
    __syncthreads();
    // phase 2: fold GEMM, A = T (LDS), Bt = Wk/Wv f32 (reg-stage convert)
    unsigned short (*Bs)[40] = (unsigned short(*)[40])(smem + 64 * 264 * 2);
    f32x4 acc2[4][2];
#pragma unroll
    for (int i = 0; i < 4; ++i) { acc2[i][0] = fzero; acc2[i][1] = fzero; }
    for (int k0 = 0; k0 < 256; k0 += 32) {
      {
        int colr = tid >> 1, half = tid & 1;
        int col = col0 + colr;
        const float* src = (col < 1024)
            ? &Wk[(size_t)col * 256 + k0 + half * 16]
            : &Wv[(size_t)(col - 1024) * 256 + k0 + half * 16];
#pragma unroll
        for (int e = 0; e < 16; e += 4) {
          float4 v = *(const float4*)(src + e);
          Bs[colr][half * 16 + e + 0] = f2b(v.x);
          Bs[colr][half * 16 + e + 1] = f2b(v.y);
          Bs[colr][half * 16 + e + 2] = f2b(v.z);
          Bs[colr][half * 16 + e + 3] = f2b(v.w);
        }
      }
      __syncthreads();
#pragma unroll
      for (int mi = 0; mi < 4; ++mi) {
        bf8 a = *(const bf8*)&T[mi * 16 + lr][k0 + lq * 8];
#pragma unroll
        for (int ni = 0; ni < 2; ++ni) {
          bf8 bb = *(const bf8*)&Bs[wave * 32 + ni * 16 + lr][lq * 8];
          acc2[mi][ni] = MFMA_B16(a, bb, acc2[mi][ni]);
        }
      }
      __syncthreads();
    }
#pragma unroll
    for (int mi = 0; mi < 4; ++mi)
#pragma unroll
      for (int ni = 0; ni < 2; ++ni) {
        int col = col0 + wave * 32 + ni * 16 + lr;
        int sec = col >> 10, cc = col & 1023;
#pragma unroll
        for (int r = 0; r < 4; ++r) {
          int row = row0 + mi * 16 + lq * 4 + r;
          Wqkv_t[(size_t)(1024 + sec * 256 + row) * 1024 + cc] = f2b(acc2[mi][ni][r]);
        }
      }
  } else if (blk == 2624) {
    // ---- bias fold: biasq[1024+n] = (bk@Wc@We)[n]; biasq[1280+n] = (bv@Wc@We)[n]
    float* tb = (float*)smem;   // tb[0..63] = bk@Wc, tb[64..127] = bv@Wc
    if (tid < 128) {
      int l = tid & 63;
      const float* bsrc = (tid < 64) ? bk : bv;
      float s = 0.f;
      for (int j = 0; j < 256; ++j) s += bsrc[j] * Wc[(size_t)j * 64 + l];
      tb[tid] = s;
    }
    __syncthreads();
    {
      float s0 = 0.f, s1 = 0.f;
      for (int l = 0; l < 64; ++l) {
        float w = We[(size_t)l * 256 + tid];
        s0 += tb[l] * w;
        s1 += tb[64 + l] * w;
      }
      biasq[1024 + tid] = s0;
      biasq[1280 + tid] = s1;
    }
  } else {
    // ---- bq copy: biasq[0..1024) = bq ----
    ((float4*)biasq)[tid] = ((const float4*)bq)[tid];
  }
}

// ---------- 1-wave 64x64 bt-GEMM: no barriers, dbuf LDS, BK=64, counted vmcnt ----
template<int MODE>
__global__ __launch_bounds__(64) void k_gemm1(const unsigned short* __restrict__ A,
                                              const unsigned short* __restrict__ Bt,
                                              const float* __restrict__ bias,
                                              unsigned short* __restrict__ C,
                                              int N, int K) {
  __shared__ __align__(16) unsigned short As[2][64 * 64];
  __shared__ __align__(16) unsigned short Bs[2][64 * 64];
  const int lane = threadIdx.x;
  const int row0 = blockIdx.y * 64, col0 = blockIdx.x * 64;
  const int lr = lane & 15, lq = lane >> 4;
  const int rsub = lane >> 3, sj = lane & 7;
  const int js = sj ^ rsub;            // swizzled chunk, loop-invariant
  const f32x4 fzero = {0.f, 0.f, 0.f, 0.f};
  f32x4 acc[4][4];
#pragma unroll
  for (int i = 0; i < 4; ++i)
#pragma unroll
    for (int j = 0; j < 4; ++j) acc[i][j] = fzero;

#define STAGE64(pb, k0)                                                        \
  {                                                                            \
    _Pragma("unroll")                                                          \
    for (int i = 0; i < 8; ++i)                                                \
      GLOAD16(&A[(size_t)(row0 + i * 8 + rsub) * K + (k0) + js * 8],           \
              &As[pb][(i * 512 + lane * 8)]);                                  \
    _Pragma("unroll")                                                          \
    for (int i = 0; i < 8; ++i)                                                \
      GLOAD16(&Bt[(size_t)(col0 + i * 8 + rsub) * K + (k0) + js * 8],          \
              &Bs[pb][(i * 512 + lane * 8)]);                                  \
  }

  STAGE64(0, 0);
  int cur = 0;
  for (int k0 = 0; k0 < K; k0 += 64) {
    if (k0 + 64 < K) {
      STAGE64(cur ^ 1, k0 + 64);
      asm volatile("s_waitcnt vmcnt(16)" ::: "memory");
    } else {
      asm volatile("s_waitcnt vmcnt(0)" ::: "memory");
    }
    __builtin_amdgcn_sched_barrier(0);
    bf8 af[2][4], bfr[2][4];
#pragma unroll
    for (int kk = 0; kk < 2; ++kk)
#pragma unroll
      for (int mi = 0; mi < 4; ++mi) {
        int ch = (kk * 4 + lq) ^ (lr & 7);
        af[kk][mi]  = *(const bf8*)&As[cur][(mi * 16 + lr) * 64 + ch * 8];
        bfr[kk][mi] = *(const bf8*)&Bs[cur][(mi * 16 + lr) * 64 + ch * 8];
      }
#pragma unroll
    for (int kk = 0; kk < 2; ++kk)
#pragma unroll
      for (int mi = 0; mi < 4; ++mi)
#pragma unroll
        for (int ni = 0; ni < 4; ++ni)
          acc[mi][ni] = MFMA_B16(af[kk][mi], bfr[kk][ni], acc[mi][ni]);
    cur ^= 1;
  }
#undef STAGE64
#pragma unroll
  for (int ni = 0; ni < 4; ++ni) {
    int col = col0 + ni * 16 + lr;
    float bv = bias[col];
#pragma unroll
    for (int mi = 0; mi < 4; ++mi)
#pragma unroll
      for (int r = 0; r < 4; ++r) {
        int row = row0 + mi * 16 + lq * 4 + r;
        float v = acc[mi][ni][r] + bv;
        if (MODE == 1 && col < 1280) v = feat(v);
        C[(size_t)row * N + col] = f2b(v);
      }
  }
}

// ---------- per-chunk KV sums only ----------
__global__ __launch_bounds__(256) void k_vkv(const unsigned short* __restrict__ qkvb,
                                             float* __restrict__ stc) {
  __shared__ unsigned short tl[64][72];   // V staging (raw bf16), [s][d]
  __shared__ float Kf[64 * 64];
  int c = blockIdx.x, g = blockIdx.y, b = blockIdx.z;
  int tid = threadIdx.x;
  int s0 = c * QB;
  {
    int j = tid >> 2, f0 = (tid & 3) * 16;
    const unsigned short* kr = &qkvb[(size_t)(b * S_ + s0 + j) * QKVW + 1024 + g * 64 + f0];
    const unsigned short* vr = &qkvb[(size_t)(b * S_ + s0 + j) * QKVW + 1280 + g * 64 + f0];
    uint4 k0_ = *(const uint4*)kr;
    uint4 k1_ = *(const uint4*)(kr + 8);
    const unsigned short* ks = (const unsigned short*)&k0_;
#pragma unroll
    for (int e = 0; e < 8; ++e) Kf[j * 64 + f0 + e] = b2f(ks[e]);
    ks = (const unsigned short*)&k1_;
#pragma unroll
    for (int e = 0; e < 8; ++e) Kf[j * 64 + f0 + 8 + e] = b2f(ks[e]);
    *(uint4*)&tl[j][f0] = *(const uint4*)vr;
    *(uint4*)&tl[j][f0 + 8] = *(const uint4*)(vr + 8);
  }
  __syncthreads();
  int d = tid >> 2, f0 = (tid & 3) * 16;
  float acc[16];
#pragma unroll
  for (int e = 0; e < 16; ++e) acc[e] = 0.f;
#pragma unroll 4
  for (int j = 0; j < QB; ++j) {
    float vv = b2f(tl[j][d]);
    const float* kfr = &Kf[j * 64 + f0];
#pragma unroll
    for (int e = 0; e < 16; ++e) acc[e] += vv * kfr[e];
  }
  size_t base = ((size_t)((b * HKV_ + g) * NC + c) * 65 + d) * 64 + f0;
#pragma unroll
  for (int e = 0; e < 16; ++e) stc[base + e] = acc[e];
  if (tid < 64) {
    float z = 0.f;
    for (int j = 0; j < QB; ++j) z += Kf[j * 64 + tid];
    stc[((size_t)((b * HKV_ + g) * NC + c) * 65 + 64) * 64 + tid] = z;
  }
}

// ---------- per-(chunk, head-pair) attention + inline exclusive prefix ----------
__global__ __launch_bounds__(512) void k_attn(const unsigned short* __restrict__ qkvb,
                                              const float* __restrict__ stc,
                                              unsigned short* __restrict__ ob) {
  __shared__ __align__(16) unsigned short Kf[64 * 64];
  __shared__ __align__(16) unsigned short Vl[64 * 64];
  __shared__ __align__(16) unsigned short Sl[64 * 64];
  __shared__ __align__(16) unsigned short P[2][64 * 64];  // V scratch / scores / O staging
  __shared__ float zl[64];
  __shared__ float qz[2][64];
  __shared__ float den[2][64];
  int c = blockIdx.x, hp = blockIdx.y, b = blockIdx.z;
  int g = hp >> 1;
  int tid = threadIdx.x, lane = tid & 63, wave = tid >> 6;
  int s0 = c * QB;
  const int lr = lane & 15, lq = lane >> 4, lk = lq * 8;
  const int hh = wave >> 2, rw = (wave & 3) * 16;
  unsigned short* Pv = &P[0][0];   // V-row scratch, stride 72

  // ---- phase A: load K -> Kf, V rows -> Pv; inline prefix -> Sl, zl ----
  {
    int t = tid & 255;
    int j = t >> 2, f0 = (t & 3) * 16;
    if (tid < 256) {
      const unsigned short* kr =
          &qkvb[(size_t)(b * S_ + s0 + j) * QKVW + 1024 + g * 64 + f0];
      *(uint4*)&Kf[SW(j, j * 64 + f0)]     = *(const uint4*)kr;
      *(uint4*)&Kf[SW(j, j * 64 + f0 + 8)] = *(const uint4*)(kr + 8);
    } else {
      const unsigned short* vr =
          &qkvb[(size_t)(b * S_ + s0 + j) * QKVW + 1280 + g * 64 + f0];
      *(uint4*)&Pv[j * 72 + f0]     = *(const uint4*)vr;
      *(uint4*)&Pv[j * 72 + f0 + 8] = *(const uint4*)(vr + 8);
    }
  }
  {
    int dd = tid >> 3, col = (tid & 7) * 8;
    const float* sb = stc + (size_t)(b * HKV_ + g) * NC * 4160 + dd * 64 + col;
    float p0[8], p1[8], p2[8], p3[8];
#pragma unroll
    for (int e = 0; e < 8; ++e) { p0[e] = 0.f; p1[e] = 0.f; p2[e] = 0.f; p3[e] = 0.f; }
    int cc = 0;
    for (; cc + 4 <= c; cc += 4) {
      const float* q0 = sb + (size_t)(cc + 0) * 4160;
      const float* q1 = sb + (size_t)(cc + 1) * 4160;
      const float* q2 = sb + (size_t)(cc + 2) * 4160;
      const float* q3 = sb + (size_t)(cc + 3) * 4160;
      float4 a0 = *(const float4*)q0, b0 = *(const float4*)(q0 + 4);
      float4 a1 = *(const float4*)q1, b1 = *(const float4*)(q1 + 4);
      float4 a2 = *(const float4*)q2, b2 = *(const float4*)(q2 + 4);
      float4 a3 = *(const float4*)q3, b3 = *(const float4*)(q3 + 4);
      p0[0] += a0.x; p0[1] += a0.y; p0[2] += a0.z; p0[3] += a0.w;
      p0[4] += b0.x; p0[5] += b0.y; p0[6] += b0.z; p0[7] += b0.w;
      p1[0] += a1.x; p1[1] += a1.y; p1[2] += a1.z; p1[3] += a1.w;
      p1[4] += b1.x; p1[5] += b1.y; p1[6] += b1.z; p1[7] += b1.w;
      p2[0] += a2.x; p2[1] += a2.y; p2[2] += a2.z; p2[3] += a2.w;
      p2[4] += b2.x; p2[5] += b2.y; p2[6] += b2.z; p2[7] += b2.w;
      p3[0] += a3.x; p3[1] += a3.y; p3[2] += a3.z; p3[3] += a3.w;
      p3[4] += b3.x; p3[5] += b3.y; p3[6] += b3.z; p3[7] += b3.w;
    }
    for (; cc < c; ++cc) {
      const float* q0 = sb + (size_t)cc * 4160;
      float4 a0 = *(const float4*)q0, b0 = *(const float4*)(q0 + 4);
      p0[0] += a0.x; p0[1] += a0.y; p0[2] += a0.z; p0[3] += a0.w;
      p0[4] += b0.x; p0[5] += b0.y; p0[6] += b0.z; p0[7] += b0.w;
    }
    unsigned short o[8];
#pragma unroll
    for (int e = 0; e < 8; ++e) o[e] = f2b(p0[e] + p1[e] + p2[e] + p3[e]);
    *(uint4*)&Sl[SW(dd, dd * 64 + col)] = *(const uint4*)o;
    if (tid < 64) {
      const float* zb = stc + (size_t)(b * HKV_ + g) * NC * 4160 + 64 * 64 + tid;
      float z0 = 0.f, z1 = 0.f, z2 = 0.f, z3 = 0.f;
      int c2 = 0;
      for (; c2 + 4 <= c; c2 += 4) {
        z0 += zb[(size_t)(c2 + 0) * 4160];
        z1 += zb[(size_t)(c2 + 1) * 4160];
        z2 += zb[(size_t)(c2 + 2) * 4160];
        z3 += zb[(size_t)(c2 + 3) * 4160];
      }
      for (; c2 < c; ++c2) z0 += zb[(size_t)c2 * 4160];
      zl[tid] = z0 + z1 + z2 + z3;
    }
  }
  // Q fragments direct from global (L2-resident qkvb)
  bf8 aQ[2];
  {
    const unsigned short* qr =
        &qkvb[(size_t)(b * S_ + s0 + rw + lr) * QKVW + (hp * 2 + hh) * 64];
    aQ[0] = *(const bf8*)(qr + lk);
    aQ[1] = *(const bf8*)(qr + 32 + lk);
  }
  __syncthreads();
  // ---- phase B: V transpose Pv -> Vl; qz = Q-row . z (register dot) ----
  {
    int d = tid >> 3, sq = (tid & 7) * 8;
    unsigned short tmp[8];
#pragma unroll
    for (int e = 0; e < 8; ++e) tmp[e] = Pv[(sq + e) * 72 + d];
    *(uint4*)&Vl[SW(d, d * 64 + sq)] = *(const uint4*)tmp;
  }
  {
    float qdot = 0.f;
#pragma unroll
    for (int kk = 0; kk < 2; ++kk)
#pragma unroll
      for (int e = 0; e < 8; ++e)
        qdot += b2f((unsigned short)aQ[kk][e]) * zl[kk * 32 + lq * 8 + e];
    qdot += __shfl_xor(qdot, 16);
    qdot += __shfl_xor(qdot, 32);
    if (lq == 0) qz[hh][rw + lr] = qdot;
  }
  __syncthreads();
  // ---- phase C: QK^T, causal mask, write scores into P ----
  const f32x4 fzero = {0.f, 0.f, 0.f, 0.f};
  f32x4 sc[4];
#pragma unroll
  for (int nj = 0; nj < 4; ++nj) sc[nj] = fzero;
#pragma unroll
  for (int nj = 0; nj < 4; ++nj)
#pragma unroll
    for (int kk = 0; kk < 2; ++kk) {
      bf8 bk8 = *(const bf8*)&Kf[SW(nj * 16 + lr, (nj * 16 + lr) * 64 + kk * 32 + lk)];
      sc[nj] = MFMA_B16(aQ[kk], bk8, sc[nj]);
    }
#pragma unroll
  for (int nj = 0; nj < 4; ++nj)
#pragma unroll
    for (int r = 0; r < 4; ++r) {
      int i = rw + lq * 4 + r;
      int j = nj * 16 + lr;
      float v = (j <= i) ? sc[nj][r] : 0.f;
      P[hh][SW(i, i * 64 + j)] = f2b(v);
    }
  __syncthreads();
  // ---- phase D: den = rowsum(P) + qz; PV + QS MFMAs ----
  {
    int hd = tid >> 8, t = tid & 255;
    int i = t >> 2, q = t & 3, f0 = q * 16;
    float s = 0.f;
#pragma unroll
    for (int e = 0; e < 16; ++e) s += b2f(P[hd][SW(i, i * 64 + f0 + e)]);
    s += __shfl_xor(s, 1);
    s += __shfl_xor(s, 2);
    if (q == 0) den[hd][i] = s + qz[hd][i];
  }
  f32x4 oa[4];
#pragma unroll
  for (int nd = 0; nd < 4; ++nd) oa[nd] = fzero;
  bf8 aP[2];
#pragma unroll
  for (int kk = 0; kk < 2; ++kk)
    aP[kk] = *(const bf8*)&P[hh][SW(rw + lr, (rw + lr) * 64 + kk * 32 + lk)];
#pragma unroll
  for (int nd = 0; nd < 4; ++nd)
#pragma unroll
    for (int kk = 0; kk < 2; ++kk) {
      bf8 bS = *(const bf8*)&Sl[SW(nd * 16 + lr, (nd * 16 + lr) * 64 + kk * 32 + lk)];
      oa[nd] = MFMA_B16(aQ[kk], bS, oa[nd]);
      bf8 bV = *(const bf8*)&Vl[SW(nd * 16 + lr, (nd * 16 + lr) * 64 + kk * 32 + lk)];
      oa[nd] = MFMA_B16(aP[kk], bV, oa[nd]);
    }
  __syncthreads();   // all P reads done; den visible
  // ---- phase E: O staging into P (flat [64][128]) ----
#pragma unroll
  for (int nd = 0; nd < 4; ++nd)
#pragma unroll
    for (int r = 0; r < 4; ++r) {
      int i = rw + lq * 4 + r;
      int dd = nd * 16 + lr;
      (&P[0][0])[i * 128 + hh * 64 + dd] = f2b(oa[nd][r] / (den[hh][i] + 1e-6f));
    }
  __syncthreads();
  // ---- phase F: coalesced store, 64 rows x 128 cols ----
  {
    int j = tid >> 3, u = tid & 7;
    unsigned short* orow = &ob[(size_t)(b * S_ + s0 + j) * D_ + hp * 128 + u * 16];
    *(uint4*)orow       = *(const uint4*)&(&P[0][0])[j * 128 + u * 16];
    *(uint4*)(orow + 8) = *(const uint4*)&(&P[0][0])[j * 128 + u * 16 + 8];
  }
}

// ------- residual + LayerNorm (bf16 x, bf16 o2) -------
__global__ __launch_bounds__(256) void k_ln(const unsigned short* __restrict__ xb,
                                            const unsigned short* __restrict__ o2,
                                            const float* __restrict__ gamma,
                                            const float* __restrict__ beta,
                                            float* __restrict__ out) {
  int row = blockIdx.x, tid = threadIdx.x;
  ushort4 xv = ((const ushort4*)(xb + (size_t)row * D_))[tid];
  ushort4 ov = ((const ushort4*)(o2 + (size_t)row * D_))[tid];
  float4 y;
  y.x = b2f(xv.x) + b2f(ov.x); y.y = b2f(xv.y) + b2f(ov.y);
  y.z = b2f(xv.z) + b2f(ov.z); y.w = b2f(xv.w) + b2f(ov.w);
  float s = y.x + y.y + y.z + y.w;
  float ss = y.x * y.x + y.y * y.y + y.z * y.z + y.w * y.w;
#pragma unroll
  for (int off = 32; off > 0; off >>= 1) {
    s += __shfl_down(s, off);
    ss += __shfl_down(ss, off);
  }
  __shared__ float red[8];
  int lane = tid & 63, wave = tid >> 6;
  if (lane == 0) { red[wave] = s; red[4 + wave] = ss; }
  __syncthreads();
  if (tid == 0) {
    red[0] = red[0] + red[1] + red[2] + red[3];
    red[4] = red[4] + red[5] + red[6] + red[7];
  }
  __syncthreads();
  float mu = red[0] * (1.f / D_);
  float var = red[4] * (1.f / D_) - mu * mu;
  float rs = rsqrtf(var + 1e-5f);
  float4 g4 = ((const float4*)gamma)[tid];
  float4 b4 = ((const float4*)beta)[tid];
  float4 o;
  o.x = (y.x - mu) * rs * g4.x + b4.x;
  o.y = (y.y - mu) * rs * g4.y + b4.y;
  o.z = (y.z - mu) * rs * g4.z + b4.z;
  o.w = (y.w - mu) * rs * g4.w + b4.w;
  ((float4*)(out + (size_t)row * D_))[tid] = o;
}

extern "C" void kernel_launch(void* const* d_in, const int* in_sizes, int n_in,
                              void* d_out, int out_size, void* d_ws, size_t ws_size,
                              hipStream_t stream) {
  const float* x     = (const float*)d_in[0];
  const float* Wq    = (const float*)d_in[1];
  const float* bq    = (const float*)d_in[2];
  const float* Wk    = (const float*)d_in[3];
  const float* bk    = (const float*)d_in[4];
  const float* Wv    = (const float*)d_in[5];
  const float* bv    = (const float*)d_in[6];
  const float* Wc    = (const float*)d_in[7];
  const float* We    = (const float*)d_in[8];
  const float* Wo    = (const float*)d_in[9];
  const float* bo    = (const float*)d_in[10];
  const float* gamma = (const float*)d_in[11];
  const float* beta  = (const float*)d_in[12];

  char* p = (char*)d_ws;
  size_t off = 0;
  auto carve = [&](size_t bytes) {
    void* r = p + off;
    off = (off + bytes + 255) & ~(size_t)255;
    return r;
  };
  unsigned short* xb     = (unsigned short*)carve((size_t)BS_ * D_ * 2);
  unsigned short* Wqkv_t = (unsigned short*)carve((size_t)QKVW * D_ * 2);
  unsigned short* Wo_t   = (unsigned short*)carve((size_t)D_ * D_ * 2);
  float*          biasq  = (float*)carve(QKVW * 4);
  unsigned short* qkvb   = (unsigned short*)carve((size_t)BS_ * QKVW * 2);
  float*          stc    = (float*)carve((size_t)8 * NC * 65 * 64 * 4);
  unsigned short* obuf   = (unsigned short*)carve((size_t)BS_ * D_ * 2);
  unsigned short* o2     = (unsigned short*)carve((size_t)BS_ * D_ * 2);

  // P1: prep + self-contained KV weight-fold + bias fold (k_fold eliminated)
  k_prep<<<2626, 256, 0, stream>>>(x, Wq, Wo, Wk, Wv, Wc, We, bq, bk, bv,
                                   xb, Wqkv_t, Wo_t, biasq);
  // P2: fused QKV projection -> qkvb bf16 (Q,K pre-featted)
  k_gemm1<1><<<dim3(24, 32), 64, 0, stream>>>(xb, Wqkv_t, biasq, qkvb, QKVW, 1024);
  // P3: per-chunk KV sums
  k_vkv<<<dim3(NC, HKV_, B_), 256, 0, stream>>>(qkvb, stc);
  // P4: attention (inline prefix; 2 heads/block)
  k_attn<<<dim3(NC, H_ / 2, B_), 512, 0, stream>>>(qkvb, stc, obuf);
  // P5: output projection -> o2 bf16
  k_gemm1<0><<<dim3(16, 32), 64, 0, stream>>>(obuf, Wo_t, bo, o2, 1024, 1024);
  // P6: residual + LayerNorm (bf16 inputs)
  k_ln<<<BS_, 256, 0, stream>>>(xb, o2, gamma, beta, (float*)d_out);
}